// Round 10
// baseline (666.620 us; speedup 1.0000x reference)
//
#include <hip/hip_runtime.h>
#include <math.h>

constexpr int kDM   = 512;
constexpr int kDI   = 1024;
constexpr int kDS   = 16;
constexpr int kDC   = 4;
constexpr int kDTR  = 32;
constexpr int kL    = 2;
constexpr int kB    = 4;
constexpr int kN    = 1024;
constexpr int kB2   = 8;              // combined batch: rows 0-3 fwd, 4-7 bwd
constexpr int kROWS = kB2 * kN;       // 8192
constexpr int kMDIR = kB * kN;        // 4096 rows per direction

enum { EPI_NONE=0, EPI_SOFTPLUS=1, EPI_RESID=2, EPI_GELU=3, EPI_RESID_BIAS=4, EPI_TANH=5 };
enum { MODE_N=0, MODE_OTR=1, MODE_DBL=2, MODE_GATE=3 };

typedef __attribute__((ext_vector_type(8))) short bf16x8;
typedef __attribute__((ext_vector_type(4))) short bf16x4;
typedef __attribute__((ext_vector_type(4))) float f32x4;

__device__ __forceinline__ unsigned short f2bf(float f) {
    unsigned int u = __float_as_uint(f);
    return (unsigned short)((u + 0x7FFFu + ((u >> 16) & 1u)) >> 16);
}
__device__ __forceinline__ float b2f(unsigned short u) {
    return __uint_as_float((unsigned int)u << 16);
}

// Abramowitz-Stegun 7.1.26 erf: max err 1.5e-7 (+ ~1e-7 from v_rcp) --
// far below bf16 LSB (2^-8 rel), replaces branchy libm erff (~50 inst -> ~14).
__device__ __forceinline__ float erf_as(float x) {
    float ax = fabsf(x);
    float t  = __builtin_amdgcn_rcpf(1.f + 0.3275911f * ax);
    float p  = t * (0.254829592f + t * (-0.284496736f + t * (1.421413741f +
               t * (-1.453152027f + t * 1.061405429f))));
    float e  = __builtin_amdgcn_exp2f(ax * ax * -1.44269504f);
    float r  = 1.f - p * e;
    return __builtin_copysignf(r, x);
}

// global -> LDS 16-B DMA (one instruction, no VGPR round-trip)
#define GLD_LDS16(gsrc, ldst) \
    __builtin_amdgcn_global_load_lds((const __attribute__((address_space(1))) void*)(gsrc), \
                                     (__attribute__((address_space(3))) void*)(ldst), 16, 0, 0)

// counted vmcnt wait + barrier (T4): never drain vmcnt to 0 in the K-loop.
// inline asm w/ "memory" clobber (rule #18: stops IR hoisting of ds_reads)
// + sched_barrier(0) (stops MIR scheduler motion).
template<int N>
__device__ __forceinline__ void wait_vm_bar() {
    if constexpr (N == 0)      asm volatile("s_waitcnt vmcnt(0)\n\ts_barrier" ::: "memory");
    else if constexpr (N == 3) asm volatile("s_waitcnt vmcnt(3)\n\ts_barrier" ::: "memory");
    else if constexpr (N == 4) asm volatile("s_waitcnt vmcnt(4)\n\ts_barrier" ::: "memory");
    else if constexpr (N == 6) asm volatile("s_waitcnt vmcnt(6)\n\ts_barrier" ::: "memory");
    else static_assert(N == 0 || N == 3 || N == 4 || N == 6, "add literal");
    __builtin_amdgcn_sched_barrier(0);
}
__device__ __forceinline__ void bar_only() {
    asm volatile("s_barrier" ::: "memory");
    __builtin_amdgcn_sched_barrier(0);
}

// ------------------------------------------------------- weight prep --------
struct WJobs { const float* s[13]; };
// job order: f_inw b_inw f_xpw b_xpw f_dtw b_dtw f_ow b_ow f_w1 b_w1 f_w2 b_w2 aw1
constexpr size_t O_INW_F = 0;
constexpr size_t O_INW_B = O_INW_F + 2u*512*2048;
constexpr size_t O_XPW_F = O_INW_B + 2u*512*2048;
constexpr size_t O_XPW_B = O_XPW_F + 2u*1024*64;
constexpr size_t O_DTW_F = O_XPW_B + 2u*1024*64;
constexpr size_t O_DTW_B = O_DTW_F + 2u*32*1024;
constexpr size_t O_OW_F  = O_DTW_B + 2u*32*1024;
constexpr size_t O_OW_B  = O_OW_F  + 2u*1024*512;
constexpr size_t O_W1_F  = O_OW_B  + 2u*1024*512;
constexpr size_t O_W1_B  = O_W1_F  + 2u*512*2048;
constexpr size_t O_W2_F  = O_W1_B  + 2u*512*2048;
constexpr size_t O_W2_B  = O_W2_F  + 2u*2048*512;
constexpr size_t O_AW1   = O_W2_B  + 2u*2048*512;
constexpr size_t O_WTOT  = O_AW1   + 1u*512*256;

__global__ __launch_bounds__(256) void wprep_k(WJobs jobs, unsigned short* __restrict__ dst)
{
    const int wK[13] = {512,512,1024,1024,32,32,1024,1024,512,512,2048,2048,512};
    const int wN[13] = {2048,2048,64,64,1024,1024,512,512,2048,2048,512,512,256};
    const int wL[13] = {2,2,2,2,2,2,2,2,2,2,2,2,1};
    int blk = blockIdx.x;
    int j = 0; int base = 0; size_t doff = 0;
    for (; j < 13; j++) {
        int nb = wL[j] * (wK[j] / 32) * (wN[j] / 32);
        if (blk < base + nb) break;
        base += nb;
        doff += (size_t)wL[j] * wK[j] * wN[j];
    }
    int rel = blk - base;
    int K = wK[j], N = wN[j];
    int tk = K / 32, tn = N / 32;
    int l = rel / (tk * tn); rel -= l * tk * tn;
    int kt = rel / tn, nt = rel - (rel / tn) * tn;
    const float* src = jobs.s[j] + (size_t)l * K * N;
    unsigned short* d = dst + doff + (size_t)l * K * N;
    __shared__ float tl[32][33];
    const int c = threadIdx.x & 31, rg = threadIdx.x >> 5;
#pragma unroll
    for (int rr = 0; rr < 4; rr++)
        tl[rg * 4 + rr][c] = src[(size_t)(kt * 32 + rg * 4 + rr) * N + nt * 32 + c];
    __syncthreads();
#pragma unroll
    for (int rr = 0; rr < 4; rr++)
        d[(size_t)(nt * 32 + rg * 4 + rr) * K + kt * 32 + c] = f2bf(tl[c][rg * 4 + rr]);
}

// ---------------------------------------------------------------- init h ----
__global__ __launch_bounds__(256) void init_h_k(const float* __restrict__ x,
                                                float* __restrict__ h)
{
    size_t idx = (size_t)blockIdx.x * 256 + threadIdx.x;   // kROWS*kDM
    int d  = idx & (kDM - 1);
    int t  = (idx >> 9) & (kN - 1);
    int bb = (int)(idx >> 19);
    int b = bb & 3, dir = bb >> 2;
    int ts = dir ? (kN - 1 - t) : t;
    h[idx] = x[((size_t)b * kN + ts) * kDM + d];
}

__global__ __launch_bounds__(256) void h2b_k(const float* __restrict__ h,
                                             unsigned short* __restrict__ o)
{
    size_t idx = (size_t)blockIdx.x * 256 + threadIdx.x;
    o[idx] = f2bf(h[idx]);
}

// ---------------------------------------------------------------- layernorm --
template<int DIM, int OBF>
__global__ __launch_bounds__(256) void ln_k(const float* __restrict__ x,
    const float* __restrict__ wf, const float* __restrict__ wb,
    const float* __restrict__ bf, const float* __restrict__ bbp,
    void* __restrict__ outv)
{
    const int row = blockIdx.x;
    const int tid = threadIdx.x;
    constexpr int PT = DIM / 256;
    const int dir = (row >= kMDIR) ? 1 : 0;
    const float* w = dir ? wb : wf;
    const float* b = dir ? bbp : bf;

    float v[PT];
    float s1 = 0.f, s2 = 0.f;
#pragma unroll
    for (int i = 0; i < PT; i++) {
        float t = x[(size_t)row * DIM + tid + i * 256];
        v[i] = t; s1 += t; s2 += t * t;
    }
    for (int o = 32; o > 0; o >>= 1) { s1 += __shfl_xor(s1, o, 64); s2 += __shfl_xor(s2, o, 64); }
    __shared__ float r1[4], r2[4];
    int wv = tid >> 6;
    if ((tid & 63) == 0) { r1[wv] = s1; r2[wv] = s2; }
    __syncthreads();
    s1 = r1[0] + r1[1] + r1[2] + r1[3];
    s2 = r2[0] + r2[1] + r2[2] + r2[3];
    float mu  = s1 / DIM;
    float var = s2 / DIM - mu * mu;
    float rr  = rsqrtf(var + 1e-5f);
#pragma unroll
    for (int i = 0; i < PT; i++) {
        int c = tid + i * 256;
        float o = (v[i] - mu) * rr * w[c] + b[c];
        if (OBF) ((unsigned short*)outv)[(size_t)row * DIM + c] = f2bf(o);
        else     ((float*)outv)[(size_t)row * DIM + c] = o;
    }
}

// ---------------------------------------------------------------- MFMA GEMM -
// C = A @ B (+bias)(+epilogue). A bf16 [M][lda], B^T bf16 [N][K].
// r19 (KB==64): counted-vmcnt 2-buffer pipeline (T4). R9's loop ended each
// K-iter with __syncthreads() == s_waitcnt vmcnt(0) -- the just-issued
// prefetch had to fully land before tile t+1 compute, giving each load only
// ~600cyc of cover for ~900cyc latency. Now: compute(t) -> barrier ->
// stage(t+2) -> wait vmcnt(NST) (t+1 landed, t+2 stays IN FLIGHT) ->
// barrier. Every load gets ~2 compute phases. LDS still 2 buffers.
template<int BM, int BN, int EPI, int ATR, int MODE, int OBF, int KB,
         int NTH = 256, int WSN = 2>
__global__ __launch_bounds__(NTH) void gemm_mfma(
    const unsigned short* __restrict__ A, int lda, int K,
    const unsigned short* __restrict__ Btf, const unsigned short* __restrict__ Btb,
    const float* __restrict__ biasf, const float* __restrict__ biasb,
    void* __restrict__ Cv, int ldc, unsigned short* __restrict__ Ct)
{
    constexpr int SK  = 40;              // padded LDS row stride (old path)
    constexpr int KT  = KB / 32;         // 32-wide sub-tiles per stage
    constexpr int CPR = KB / 8;          // 8-elem chunks per row (old path)
    constexpr int WAVES = NTH / 64;
    constexpr int WSM = WAVES / WSN;
    constexpr int WM  = BM / WSM, WN = BN / WSN;
    constexpr int MT  = WM / 16, NT = WN / 16;
    constexpr int ASL = (BM * KB) / (NTH * 8);
    constexpr int BSL = (BN * KB) / (NTH * 8);
    constexpr int ABUF = BM * 64;        // one K-tile of A (ushorts)
    constexpr int BBUF = BN * 64;
    constexpr int ASZ = (KB == 64) ? 2 * ABUF : KT * BM * SK;
    constexpr int BSZ = (KB == 64) ? 2 * BBUF : KT * BN * SK;

    __shared__ __align__(16) unsigned short As[ASZ];
    __shared__ __align__(16) unsigned short Bs[BSZ];

    const int tid  = threadIdx.x;
    // ---- XCD swizzle (T1, bijective: nwg % 8 == 0 for every launch here) --
    const int gx   = gridDim.x;
    const int nwg  = gx * gridDim.y;
    const int lin  = blockIdx.x + blockIdx.y * gx;
    const int swz  = (lin & 7) * (nwg >> 3) + (lin >> 3);
    const int by   = swz / gx;
    const int bx   = swz - by * gx;
    const int n0   = bx * BN;
    const int row0 = by * BM;
    const int dir  = (row0 >= kMDIR) ? 1 : 0;
    const unsigned short* __restrict__ Bt = dir ? Btb : Btf;
    const float* bias = dir ? biasb : biasf;

    const int lane = tid & 63;
    const int wave = tid >> 6;
    const int wr = wave / WSN, wc = wave % WSN;
    const int ml = lane & 15, q = lane >> 4;

    f32x4 acc[MT][NT];
#pragma unroll
    for (int i = 0; i < MT; i++)
#pragma unroll
        for (int j = 0; j < NT; j++)
#pragma unroll
            for (int r = 0; r < 4; r++) acc[i][j][r] = 0.f;

    if constexpr (KB == 64) {
        // ---- counted-vmcnt 2-buffer DMA K-loop ----
        constexpr int ACW = (BM / 8) / WAVES;   // 1-KB chunks per wave (A)
        constexpr int BCW = (BN / 8) / WAVES;   // 1-KB chunks per wave (B)
        constexpr int NST = ACW + BCW;          // DMAs per wave per stage
        const int lrow = lane >> 3;                       // 0..7 row in chunk
        const int lcol = ((lane & 7) ^ (lrow & 7)) << 4;  // pre-swizzled col byte
        const char* aS[ACW ? ACW : 1];
        const char* bS[BCW ? BCW : 1];
#pragma unroll
        for (int ch = 0; ch < ACW; ch++) {
            const int chunk = wave * ACW + ch;
            aS[ch] = (const char*)A + (size_t)(row0 + chunk * 8 + lrow) * lda * 2 + lcol;
        }
#pragma unroll
        for (int ch = 0; ch < BCW; ch++) {
            const int chunk = wave * BCW + ch;
            bS[ch] = (const char*)Bt + (size_t)(n0 + chunk * 8 + lrow) * K * 2 + lcol;
        }
        const int axor = (ml & 7) << 3;  // read-side swizzle (ushort units)

        auto stage = [&](int buf) {
#pragma unroll
            for (int ch = 0; ch < ACW; ch++) {
                GLD_LDS16(aS[ch], &As[buf * ABUF + (wave * ACW + ch) * 512]);
                aS[ch] += 128;
            }
#pragma unroll
            for (int ch = 0; ch < BCW; ch++) {
                GLD_LDS16(bS[ch], &Bs[buf * BBUF + (wave * BCW + ch) * 512]);
                bS[ch] += 128;
            }
        };

        const int NKT = K >> 6;
        stage(0);
        if (NKT > 1) { stage(1); wait_vm_bar<NST>(); }
        else         { wait_vm_bar<0>(); }
        int cur = 0;
        for (int t = 0; t < NKT; t++) {
            // compute tile t from buf cur (staged & visible)
#pragma unroll
            for (int kk = 0; kk < 2; kk++) {
                bf16x8 af[MT], bfr[NT];
#pragma unroll
                for (int i = 0; i < MT; i++)
                    af[i] = *(bf16x8*)&As[cur * ABUF + (wr * WM + i * 16 + ml) * 64 + ((kk * 32 + q * 8) ^ axor)];
#pragma unroll
                for (int j = 0; j < NT; j++)
                    bfr[j] = *(bf16x8*)&Bs[cur * BBUF + (wc * WN + j * 16 + ml) * 64 + ((kk * 32 + q * 8) ^ axor)];
#pragma unroll
                for (int i = 0; i < MT; i++)
#pragma unroll
                    for (int j = 0; j < NT; j++)
                        acc[i][j] = __builtin_amdgcn_mfma_f32_16x16x32_bf16(af[i], bfr[j], acc[i][j], 0, 0, 0);
            }
            if (t + 2 < NKT) {
                bar_only();              // all waves done reading buf cur
                stage(cur);              // tile t+2 -> cur (stays in flight)
                wait_vm_bar<NST>();      // tile t+1 landed; t+2 outstanding
            } else if (t + 1 < NKT) {
                wait_vm_bar<0>();        // drain final stage
            }
            cur ^= 1;
        }
    } else {
        // ---- old reg-staging path (KB==32: dtw GEMM only, NTH==256) ----
        for (int kt = 0; kt < K; kt += KB) {
            bf16x8 a_ld[ASL ? ASL : 1];
#pragma unroll
            for (int r = 0; r < ASL; r++) {
                int i = tid + r * NTH;
                int m = i / CPR, c8 = (i % CPR) * 8;
                a_ld[r] = *(const bf16x8*)(A + (size_t)(row0 + m) * lda + kt + c8);
            }
            bf16x8 b_ld[BSL ? BSL : 1];
#pragma unroll
            for (int r = 0; r < BSL; r++) {
                int i = tid + r * NTH;
                int n = i / CPR, c8 = (i % CPR) * 8;
                b_ld[r] = *(const bf16x8*)(Bt + (size_t)(n0 + n) * K + kt + c8);
            }
            __syncthreads();
#pragma unroll
            for (int r = 0; r < ASL; r++) {
                int i = tid + r * NTH;
                int m = i / CPR, c8 = (i % CPR) * 8;
                *(bf16x8*)&As[((c8 >> 5) * BM + m) * SK + (c8 & 31)] = a_ld[r];
            }
#pragma unroll
            for (int r = 0; r < BSL; r++) {
                int i = tid + r * NTH;
                int n = i / CPR, c8 = (i % CPR) * 8;
                *(bf16x8*)&Bs[((c8 >> 5) * BN + n) * SK + (c8 & 31)] = b_ld[r];
            }
            __syncthreads();
#pragma unroll
            for (int kk = 0; kk < KT; kk++) {
                bf16x8 af[MT], bfr[NT];
#pragma unroll
                for (int i = 0; i < MT; i++)
                    af[i] = *(bf16x8*)&As[(kk * BM + wr * WM + i * 16 + ml) * SK + q * 8];
#pragma unroll
                for (int j = 0; j < NT; j++)
                    bfr[j] = *(bf16x8*)&Bs[(kk * BN + wc * WN + j * 16 + ml) * SK + q * 8];
#pragma unroll
                for (int i = 0; i < MT; i++)
#pragma unroll
                    for (int j = 0; j < NT; j++)
                        acc[i][j] = __builtin_amdgcn_mfma_f32_16x16x32_bf16(af[i], bfr[j], acc[i][j], 0, 0, 0);
            }
            __syncthreads();
        }
    }

    // ---- epilogue ----
    float* Cf = (float*)Cv;
    unsigned short* Cb = (unsigned short*)Cv;
#pragma unroll
    for (int j = 0; j < NT; j++) {
        int col = n0 + wc * WN + j * 16 + ml;
        float bv = 0.f;
        if (EPI == EPI_SOFTPLUS || EPI == EPI_GELU || EPI == EPI_RESID_BIAS || EPI == EPI_TANH)
            bv = bias[col];
#pragma unroll
        for (int i = 0; i < MT; i++) {
            int rw = row0 + wr * WM + i * 16 + q * 4;
            float v4[4];
#pragma unroll
            for (int r = 0; r < 4; r++) {
                float v = acc[i][j][r] + bv;
                if (EPI == EPI_SOFTPLUS) v = (v > 20.f) ? v : __logf(1.f + __expf(v));
                if (EPI == EPI_GELU)     v = 0.5f * v * (1.f + erf_as(v * 0.70710678118654752f));
                if (EPI == EPI_TANH)     v = tanhf(v);
                v4[r] = v;
            }
            if (MODE == MODE_GATE && n0 >= kDI) {
                // silu(z) -> gate row-major [row][kDI]
#pragma unroll
                for (int r = 0; r < 4; r++) {
                    float sv = v4[r] / (1.f + __expf(-v4[r]));
                    Ct[(size_t)(rw + r) * kDI + (col - kDI)] = f2bf(sv);
                }
            } else {
#pragma unroll
                for (int r = 0; r < 4; r++) {
                    size_t o = (size_t)(rw + r) * ldc + col;
                    if (EPI == EPI_RESID || EPI == EPI_RESID_BIAS) Cf[o] += v4[r];
                    else if (OBF) Cb[o] = f2bf(v4[r]);
                    else Cf[o] = v4[r];
                }
                if (MODE == MODE_DBL && col >= 32) {
                    float* F = (float*)Ct;          // dblF f32 [row][32]
#pragma unroll
                    for (int r = 0; r < 4; r++)
                        F[(size_t)(rw + r) * 32 + (col - 32)] = v4[r];
                }
            }
        }
    }
}

// ---------------------------------------------------------------- conv ------
// xb bf16 [row][kDI] (x-half) -> xh bf16 [row][kDI] = silu(causal conv + cb).
__global__ __launch_bounds__(256) void conv_k(const unsigned short* __restrict__ xb,
    const float* __restrict__ cwf, const float* __restrict__ cwb,
    const float* __restrict__ cbf, const float* __restrict__ cbb,
    unsigned short* __restrict__ xh)
{
    __shared__ float tl[67][33];
    const int t0 = blockIdx.x * 64, d0 = blockIdx.y * 32, bb = blockIdx.z;
    const int dir = bb >> 2;
    const float* cw = dir ? cwb : cwf;
    const float* cb = dir ? cbb : cbf;
    const int dl = threadIdx.x & 31, rl = threadIdx.x >> 5;
    const size_t base = (size_t)bb * kN * kDI + d0 + dl;
#pragma unroll
    for (int p = 0; p < 9; p++) {
        int r = p * 8 + rl;
        if (r < 67) {
            int ts = t0 + r - 3;
            tl[r][dl] = (ts >= 0) ? b2f(xb[base + (size_t)ts * kDI]) : 0.f;
        }
    }
    __syncthreads();
    const int gd = d0 + dl;
    float c0 = cw[gd*4+0], c1 = cw[gd*4+1], c2 = cw[gd*4+2], c3 = cw[gd*4+3];
    float bv = cb[gd];
#pragma unroll
    for (int jj = 0; jj < 8; jj++) {
        int tt = rl + 8 * jj;
        float acc = bv + c0*tl[tt][dl] + c1*tl[tt+1][dl] + c2*tl[tt+2][dl] + c3*tl[tt+3][dl];
        float o = acc / (1.f + __expf(-acc));
        xh[(size_t)(bb * kN + t0 + tt) * kDI + gd] = f2bf(o);
    }
}

// ---------------------------------------------------------------- scan ------
// r14 coalesced blocked scan (validated): h[16]-in-registers 3-pass
// decomposition, all streams [row][d] row-major.
constexpr int kG  = 32;           // groups per chain
constexpr int kTg = kN / kG;      // 32 timesteps per group

template<int PASS>
__global__ __launch_bounds__(256) void bscan_k(
    const unsigned short* __restrict__ dt,   // [row][kDI]
    const unsigned short* __restrict__ xh,   // [row][kDI]
    const unsigned short* __restrict__ gate, // [row][kDI]
    const float* __restrict__ dblF,          // [row][32] (B | C)
    unsigned short* __restrict__ y,          // [row][kDI]
    float* __restrict__ PL,                  // [bb][g][32 slots][kDI]
    const float* __restrict__ alogf, const float* __restrict__ alogb,
    const float* __restrict__ ddf,   const float* __restrict__ ddb)
{
    const int d  = blockIdx.x * 256 + threadIdx.x;   // 0..1023
    const int g  = blockIdx.y;                       // 0..31
    const int bb = blockIdx.z;                       // 0..7
    const int dir = bb >> 2;
    const float* alog = dir ? alogb : alogf;
    const float* ddp  = dir ? ddb  : ddf;

    float a2[16];
#pragma unroll
    for (int s = 0; s < 16; s += 4) {
        float4 al = *(const float4*)&alog[d * kDS + s];
        a2[s+0] = -__expf(al.x) * 1.44269504f;
        a2[s+1] = -__expf(al.y) * 1.44269504f;
        a2[s+2] = -__expf(al.z) * 1.44269504f;
        a2[s+3] = -__expf(al.w) * 1.44269504f;
    }

    const size_t plb = (size_t)(bb * kG + g) * 32 * kDI + d;   // slot stride kDI
    float h[16];
    if (PASS == 0) {
#pragma unroll
        for (int s = 0; s < 16; s++) h[s] = 0.f;
    } else {
#pragma unroll
        for (int s = 0; s < 16; s++) h[s] = PL[plb + (size_t)(16 + s) * kDI];
    }

    const int row0 = bb * kN + g * kTg;
    const unsigned short* pd = dt   + (size_t)row0 * kDI + d;
    const unsigned short* px = xh   + (size_t)row0 * kDI + d;
    const unsigned short* pg = gate + (size_t)row0 * kDI + d;
    const float* pbc = dblF + (size_t)row0 * 32;
    unsigned short* py = y + (size_t)row0 * kDI + d;
    const float ddv = ddp[d];
    float sdt = 0.f;

#pragma unroll 4
    for (int t = 0; t < kTg; t++) {
        float dtv = b2f(pd[(size_t)t * kDI]);
        float xvv = b2f(px[(size_t)t * kDI]);
        float dtx = dtv * xvv;
        const float* bc = pbc + t * 32;
        if (PASS == 0) {
            sdt += dtv;
#pragma unroll
            for (int s4 = 0; s4 < 4; s4++) {
                float4 Bq = *(const float4*)(bc + s4 * 4);
                h[s4*4+0] = __builtin_amdgcn_exp2f(dtv * a2[s4*4+0]) * h[s4*4+0] + dtx * Bq.x;
                h[s4*4+1] = __builtin_amdgcn_exp2f(dtv * a2[s4*4+1]) * h[s4*4+1] + dtx * Bq.y;
                h[s4*4+2] = __builtin_amdgcn_exp2f(dtv * a2[s4*4+2]) * h[s4*4+2] + dtx * Bq.z;
                h[s4*4+3] = __builtin_amdgcn_exp2f(dtv * a2[s4*4+3]) * h[s4*4+3] + dtx * Bq.w;
            }
        } else {
            float p = 0.f;
#pragma unroll
            for (int s4 = 0; s4 < 4; s4++) {
                float4 Bq = *(const float4*)(bc + s4 * 4);
                float4 Cq = *(const float4*)(bc + 16 + s4 * 4);
                h[s4*4+0] = __builtin_amdgcn_exp2f(dtv * a2[s4*4+0]) * h[s4*4+0] + dtx * Bq.x;
                p += h[s4*4+0] * Cq.x;
                h[s4*4+1] = __builtin_amdgcn_exp2f(dtv * a2[s4*4+1]) * h[s4*4+1] + dtx * Bq.y;
                p += h[s4*4+1] * Cq.y;
                h[s4*4+2] = __builtin_amdgcn_exp2f(dtv * a2[s4*4+2]) * h[s4*4+2] + dtx * Bq.z;
                p += h[s4*4+2] * Cq.z;
                h[s4*4+3] = __builtin_amdgcn_exp2f(dtv * a2[s4*4+3]) * h[s4*4+3] + dtx * Bq.w;
                p += h[s4*4+3] * Cq.w;
            }
            float gvv = b2f(pg[(size_t)t * kDI]);
            py[(size_t)t * kDI] = f2bf((p + ddv * xvv) * gvv);
        }
    }

    if (PASS == 0) {
#pragma unroll
        for (int s = 0; s < 16; s++) {
            PL[plb + (size_t)s * kDI]        = __builtin_amdgcn_exp2f(a2[s] * sdt);
            PL[plb + (size_t)(16 + s) * kDI] = h[s];
        }
    }
}

// boundary fix: h_in[chain][g] = scan of (P,L) over groups; rewrites L slot.
__global__ __launch_bounds__(256) void bfix_k(float* __restrict__ PL)
{
    const int idx = blockIdx.x * 256 + threadIdx.x;  // 16 s x 8 bb x 1024 d
    const int d  = idx & (kDI - 1);
    const int bb = (idx >> 10) & 7;
    const int s  = idx >> 13;
    float h = 0.f;
    for (int g = 0; g < kG; g++) {
        size_t base = (size_t)(bb * kG + g) * 32 * kDI + d;
        float P = PL[base + (size_t)s * kDI];
        float L = PL[base + (size_t)(16 + s) * kDI];
        PL[base + (size_t)(16 + s) * kDI] = h;   // h_in for pass C
        h = P * h + L;
    }
}

// ---------------------------------------------------------------- attention -
__global__ __launch_bounds__(64) void att_score_k(const unsigned short* __restrict__ tmp,
    const float* __restrict__ aw2, const float* __restrict__ ab2,
    float* __restrict__ score)
{
    int row = blockIdx.x, lane = threadIdx.x;
    float acc = 0.f;
#pragma unroll
    for (int j = 0; j < 4; j++)
        acc += b2f(tmp[(size_t)row * 256 + lane + j * 64]) * aw2[lane + j * 64];
    for (int o = 32; o > 0; o >>= 1) acc += __shfl_xor(acc, o, 64);
    if (lane == 0) score[row] = acc + ab2[0];
}

__global__ __launch_bounds__(256) void softmax_k(const float* __restrict__ score,
                                                 float* __restrict__ w)
{
    int bb = blockIdx.x, tid = threadIdx.x;
    float v[4]; float m = -1e30f;
#pragma unroll
    for (int i = 0; i < 4; i++) { v[i] = score[bb * kN + tid + i * 256]; m = fmaxf(m, v[i]); }
    for (int o = 32; o > 0; o >>= 1) m = fmaxf(m, __shfl_xor(m, o, 64));
    __shared__ float r1[4], r2[4];
    int wv = tid >> 6;
    if ((tid & 63) == 0) r1[wv] = m;
    __syncthreads();
    m = fmaxf(fmaxf(r1[0], r1[1]), fmaxf(r1[2], r1[3]));
    float s = 0.f;
#pragma unroll
    for (int i = 0; i < 4; i++) { v[i] = __expf(v[i] - m); s += v[i]; }
    for (int o = 32; o > 0; o >>= 1) s += __shfl_xor(s, o, 64);
    if ((tid & 63) == 0) r2[wv] = s;
    __syncthreads();
    s = r2[0] + r2[1] + r2[2] + r2[3];
    float inv = 1.f / s;
#pragma unroll
    for (int i = 0; i < 4; i++) w[bb * kN + tid + i * 256] = v[i] * inv;
}

__global__ __launch_bounds__(512) void pool_k(const float* __restrict__ w,
    const float* __restrict__ h, float* zcat)
{
    int bb = blockIdx.x, chunk = blockIdx.y;   // 8 x 32
    int d = threadIdx.x;
    float acc = 0.f;
    int n0 = chunk * 32;
    for (int n = n0; n < n0 + 32; n++)
        acc += w[bb * kN + n] * h[((size_t)bb * kN + n) * kDM + d];
    int b = bb & 3, dir = bb >> 2;
    atomicAdd(&zcat[b * (2 * kDM) + dir * kDM + d], acc);
}

__global__ __launch_bounds__(256) void att_out_k(const float* __restrict__ w,
                                                 float* __restrict__ out)
{
    int idx = blockIdx.x * 256 + threadIdx.x;  // kB*kN
    int b = idx >> 10, n = idx & 1023;
    out[idx] = 0.5f * (w[b * kN + n] + w[(b + 4) * kN + (kN - 1 - n)]);
}

// ---------------------------------------------------------------- launch ----
extern "C" void kernel_launch(void* const* d_in, const int* in_sizes, int n_in,
                              void* d_out, int out_size, void* d_ws, size_t ws_size,
                              hipStream_t stream)
{
    const float* x = (const float*)d_in[0];
    const float* fp[17]; const float* bp[17];
    for (int i = 0; i < 17; i++) { fp[i] = (const float*)d_in[1 + i]; bp[i] = (const float*)d_in[18 + i]; }
    const float* aw1 = (const float*)d_in[35];
    const float* ab1 = (const float*)d_in[36];
    const float* aw2 = (const float*)d_in[37];
    const float* ab2 = (const float*)d_in[38];
    const float* nw  = (const float*)d_in[39];
    const float* nb  = (const float*)d_in[40];
    float* out = (float*)d_out;

    float* h = (float*)d_ws;                                   // 8192*512 f32
    unsigned short* ub    = (unsigned short*)(h + (size_t)kROWS * kDM);  // 8192*512
    unsigned short* xbuf  = ub    + (size_t)kROWS * kDM;        // 8192*1024 (x-half / y / ffn1 lo)
    unsigned short* tbuf  = xbuf  + (size_t)kROWS * kDI;        // 8192*1024 (dt / ffn1 hi / hb)
    unsigned short* xhb   = tbuf  + (size_t)kROWS * kDI;        // 8192*1024 (xh row-major)
    unsigned short* gateb = xhb   + (size_t)kROWS * kDI;        // 8192*1024 (gate row-major)
    unsigned short* dbl   = gateb + (size_t)kROWS * kDI;        // 8192*64 bf16
    float* dblF  = (float*)(dbl + (size_t)kROWS * 64);          // 8192*32 f32 (B/C)
    float* score = dblF + (size_t)kROWS * 32;                   // 8192
    float* smw   = score + kROWS;                               // 8192
    float* zcat  = smw   + kROWS;                               // 4096
    unsigned short* wts  = (unsigned short*)(zcat + kB * 2 * kDM);
    float* PL = (float*)(wts + O_WTOT);                         // 8*32*32*1024 f32 = 32MB

    // ---- weight prep: fp32 [L][K][N] -> bf16 [L][N][K] (one launch) ----
    WJobs jobs;
    jobs.s[0] = fp[2];  jobs.s[1] = bp[2];
    jobs.s[2] = fp[5];  jobs.s[3] = bp[5];
    jobs.s[4] = fp[6];  jobs.s[5] = bp[6];
    jobs.s[6] = fp[10]; jobs.s[7] = bp[10];
    jobs.s[8] = fp[13]; jobs.s[9] = bp[13];
    jobs.s[10] = fp[15]; jobs.s[11] = bp[15];
    jobs.s[12] = aw1;
    int wblocks = 0;
    {
        const int wK[13] = {512,512,1024,1024,32,32,1024,1024,512,512,2048,2048,512};
        const int wN[13] = {2048,2048,64,64,1024,1024,512,512,2048,2048,512,512,256};
        const int wL[13] = {2,2,2,2,2,2,2,2,2,2,2,2,1};
        for (int j = 0; j < 13; j++) wblocks += wL[j] * (wK[j]/32) * (wN[j]/32);
    }
    wprep_k<<<wblocks, 256, 0, stream>>>(jobs, wts);

    init_h_k<<<kROWS * kDM / 256, 256, 0, stream>>>(x, h);

    for (int l = 0; l < kL; l++) {
        const float *f_n1w = fp[0]  + l * kDM,            *b_n1w = bp[0]  + l * kDM;
        const float *f_n1b = fp[1]  + l * kDM,            *b_n1b = bp[1]  + l * kDM;
        const float *f_cw  = fp[3]  + l * kDI * kDC,      *b_cw  = bp[3]  + l * kDI * kDC;
        const float *f_cb  = fp[4]  + l * kDI,            *b_cb  = bp[4]  + l * kDI;
        const float *f_dtb = fp[7]  + l * kDI,            *b_dtb = bp[7]  + l * kDI;
        const float *f_alog= fp[8]  + l * kDI * kDS,      *b_alog= bp[8]  + l * kDI * kDS;
        const float *f_dd  = fp[9]  + l * kDI,            *b_dd  = bp[9]  + l * kDI;
        const float *f_n2w = fp[11] + l * kDM,            *b_n2w = bp[11] + l * kDM;
        const float *f_n2b = fp[12] + l * kDM,            *b_n2b = bp[12] + l * kDM;
        const float *f_b1  = fp[14] + l * 4 * kDM,        *b_b1  = bp[14] + l * 4 * kDM;
        const float *f_b2  = fp[16] + l * kDM,            *b_b2  = bp[16] + l * kDM;

        const unsigned short *wInwF = wts + O_INW_F + (size_t)l * 2048 * 512;
        const unsigned short *wInwB = wts + O_INW_B + (size_t)l * 2048 * 512;
        const unsigned short *wXpwF = wts + O_XPW_F + (size_t)l * 64 * 1024;
        const unsigned short *wXpwB = wts + O_XPW_B + (size_t)l * 64 * 1024;
        const unsigned short *wDtwF = wts + O_DTW_F + (size_t)l * 1024 * 32;
        const unsigned short *wDtwB = wts + O_DTW_B + (size_t)l * 1024 * 32;
        const unsigned short *wOwF  = wts + O_OW_F  + (size_t)l * 512 * 1024;
        const unsigned short *wOwB  = wts + O_OW_B  + (size_t)l * 512 * 1024;
        const unsigned short *wW1F  = wts + O_W1_F  + (size_t)l * 2048 * 512;
        const unsigned short *wW1B  = wts + O_W1_B  + (size_t)l * 2048 * 512;
        const unsigned short *wW2F  = wts + O_W2_F  + (size_t)l * 512 * 2048;
        const unsigned short *wW2B  = wts + O_W2_B  + (size_t)l * 512 * 2048;

        // u = LN1(h) -> bf16
        ln_k<kDM,1><<<kROWS, 256, 0, stream>>>(h, f_n1w, b_n1w, f_n1b, b_n1b, ub);
        // x-half -> xbuf bf16 [row][kDI]; z-half -> gateb = silu(z) row-major
        // 512-thread / 8-wave blocks (2M x 4N): 4 waves/SIMD at 2 blocks/CU
        gemm_mfma<128,128,EPI_NONE,0,MODE_GATE,1,64,512,4><<<dim3(16, 64), 512, 0, stream>>>(
            ub, kDM, kDM, wInwF, wInwB, nullptr, nullptr, xbuf, kDI, gateb);
        // xh[row][kDI] = silu(conv(xbuf) + cb)  (row-major, no transpose)
        conv_k<<<dim3(kN/64, kDI/32, kB2), 256, 0, stream>>>(
            xbuf, f_cw, b_cw, f_cb, b_cb, xhb);
        // dbl = xh @ xpw (A row-major); cols>=32 also -> dblF f32 [row][32]
        gemm_mfma<32,64,EPI_NONE,0,MODE_DBL,1,64><<<dim3(1, 256), 256, 0, stream>>>(
            xhb, kDI, kDI, wXpwF, wXpwB, nullptr, nullptr, dbl, 64, (unsigned short*)dblF);
        // dt[row][kDI] = softplus(dbl[:, :32] @ dtw + dtb)  (row-major)
        gemm_mfma<128,128,EPI_SOFTPLUS,0,MODE_N,1,32><<<dim3(8, 64), 256, 0, stream>>>(
            dbl, 64, kDTR, wDtwF, wDtwB, f_dtb, b_dtb, tbuf, kDI, nullptr);
        // blocked scan: local pass -> boundary fix -> full pass (y into xbuf)
        bscan_k<0><<<dim3(kDI/256, kG, kB2), 256, 0, stream>>>(
            tbuf, xhb, gateb, dblF, xbuf, PL, f_alog, b_alog, f_dd, b_dd);
        bfix_k<<<kB2 * kDI * kDS / 256, 256, 0, stream>>>(PL);
        bscan_k<1><<<dim3(kDI/256, kG, kB2), 256, 0, stream>>>(
            tbuf, xhb, gateb, dblF, xbuf, PL, f_alog, b_alog, f_dd, b_dd);
        // h += y @ ow  (512-thread / 8-wave blocks, 4M x 2N)
        gemm_mfma<128,64,EPI_RESID,0,MODE_N,0,64,512,2><<<dim3(8, 64), 512, 0, stream>>>(
            xbuf, kDI, kDI, wOwF, wOwB, nullptr, nullptr, h, kDM, nullptr);
        // u = LN2(h) -> bf16
        ln_k<kDM,1><<<kROWS, 256, 0, stream>>>(h, f_n2w, b_n2w, f_n2b, b_n2b, ub);
        // ffn1: gelu(u @ w1 + b1) -> xbuf..tbuf slab bf16 (8192 x 2048)
        gemm_mfma<128,128,EPI_GELU,0,MODE_N,1,64,512,4><<<dim3(16, 64), 512, 0, stream>>>(
            ub, kDM, kDM, wW1F, wW1B, f_b1, b_b1, xbuf, 4*kDM, nullptr);
        // h += ffn1 @ w2 + b2  (512-thread / 8-wave blocks, 4M x 2N)
        gemm_mfma<128,64,EPI_RESID_BIAS,0,MODE_N,0,64,512,2><<<dim3(8, 64), 512, 0, stream>>>(
            xbuf, 4*kDM, 4*kDM, wW2F, wW2B, f_b2, b_b2, h, kDM, nullptr);
    }

    // attention: hb = bf16(h); u = tanh(hb @ aw1 + ab1) bf16
    h2b_k<<<kROWS * kDM / 256, 256, 0, stream>>>(h, tbuf);
    // 64x128 tile -> 256 blocks
    gemm_mfma<64,128,EPI_TANH,0,MODE_N,1,64><<<dim3(2, 128), 256, 0, stream>>>(
        tbuf, kDM, kDM, wts + O_AW1, wts + O_AW1, ab1, ab1, ub, 256, nullptr);
    att_score_k<<<kROWS, 64, 0, stream>>>(ub, aw2, ab2, score);
    softmax_k<<<kB2, 256, 0, stream>>>(score, smw);
    hipMemsetAsync(zcat, 0, kB * 2 * kDM * sizeof(float), stream);
    pool_k<<<dim3(kB2, 32), 512, 0, stream>>>(smw, h, zcat);
    // out[0:4096] = LN(concat(zf, zb))
    ln_k<2*kDM,0><<<kB, 256, 0, stream>>>(zcat, nw, nw, nb, nb, out);
    // out[4096:8192] = 0.5*(af + flip(ab))
    att_out_k<<<kB * kN / 256, 256, 0, stream>>>(smw, out + kB * 2 * kDM);
}

// Round 11
// 650.665 us; speedup vs baseline: 1.0245x; 1.0245x over previous
//
#include <hip/hip_runtime.h>
#include <math.h>

constexpr int kDM   = 512;
constexpr int kDI   = 1024;
constexpr int kDS   = 16;
constexpr int kDC   = 4;
constexpr int kDTR  = 32;
constexpr int kL    = 2;
constexpr int kB    = 4;
constexpr int kN    = 1024;
constexpr int kB2   = 8;              // combined batch: rows 0-3 fwd, 4-7 bwd
constexpr int kROWS = kB2 * kN;       // 8192
constexpr int kMDIR = kB * kN;        // 4096 rows per direction

enum { EPI_NONE=0, EPI_SOFTPLUS=1, EPI_RESID=2, EPI_GELU=3, EPI_RESID_BIAS=4, EPI_TANH=5 };
enum { MODE_N=0, MODE_OTR=1, MODE_DBL=2, MODE_GATE=3 };

typedef __attribute__((ext_vector_type(8))) short bf16x8;
typedef __attribute__((ext_vector_type(4))) short bf16x4;
typedef __attribute__((ext_vector_type(4))) float f32x4;

__device__ __forceinline__ unsigned short f2bf(float f) {
    unsigned int u = __float_as_uint(f);
    return (unsigned short)((u + 0x7FFFu + ((u >> 16) & 1u)) >> 16);
}
__device__ __forceinline__ float b2f(unsigned short u) {
    return __uint_as_float((unsigned int)u << 16);
}

// Abramowitz-Stegun 7.1.26 erf: max err 1.5e-7 (+ ~1e-7 from v_rcp) --
// far below bf16 LSB (2^-8 rel), replaces branchy libm erff (~50 inst -> ~14).
__device__ __forceinline__ float erf_as(float x) {
    float ax = fabsf(x);
    float t  = __builtin_amdgcn_rcpf(1.f + 0.3275911f * ax);
    float p  = t * (0.254829592f + t * (-0.284496736f + t * (1.421413741f +
               t * (-1.453152027f + t * 1.061405429f))));
    float e  = __builtin_amdgcn_exp2f(ax * ax * -1.44269504f);
    float r  = 1.f - p * e;
    return __builtin_copysignf(r, x);
}

// global -> LDS 16-B DMA (one instruction, no VGPR round-trip)
#define GLD_LDS16(gsrc, ldst) \
    __builtin_amdgcn_global_load_lds((const __attribute__((address_space(1))) void*)(gsrc), \
                                     (__attribute__((address_space(3))) void*)(ldst), 16, 0, 0)

// ------------------------------------------------------- weight prep --------
struct WJobs { const float* s[13]; };
// job order: f_inw b_inw f_xpw b_xpw f_dtw b_dtw f_ow b_ow f_w1 b_w1 f_w2 b_w2 aw1
constexpr size_t O_INW_F = 0;
constexpr size_t O_INW_B = O_INW_F + 2u*512*2048;
constexpr size_t O_XPW_F = O_INW_B + 2u*512*2048;
constexpr size_t O_XPW_B = O_XPW_F + 2u*1024*64;
constexpr size_t O_DTW_F = O_XPW_B + 2u*1024*64;
constexpr size_t O_DTW_B = O_DTW_F + 2u*32*1024;
constexpr size_t O_OW_F  = O_DTW_B + 2u*32*1024;
constexpr size_t O_OW_B  = O_OW_F  + 2u*1024*512;
constexpr size_t O_W1_F  = O_OW_B  + 2u*1024*512;
constexpr size_t O_W1_B  = O_W1_F  + 2u*512*2048;
constexpr size_t O_W2_F  = O_W1_B  + 2u*512*2048;
constexpr size_t O_W2_B  = O_W2_F  + 2u*2048*512;
constexpr size_t O_AW1   = O_W2_B  + 2u*2048*512;
constexpr size_t O_WTOT  = O_AW1   + 1u*512*256;

__global__ __launch_bounds__(256) void wprep_k(WJobs jobs, unsigned short* __restrict__ dst)
{
    const int wK[13] = {512,512,1024,1024,32,32,1024,1024,512,512,2048,2048,512};
    const int wN[13] = {2048,2048,64,64,1024,1024,512,512,2048,2048,512,512,256};
    const int wL[13] = {2,2,2,2,2,2,2,2,2,2,2,2,1};
    int blk = blockIdx.x;
    int j = 0; int base = 0; size_t doff = 0;
    for (; j < 13; j++) {
        int nb = wL[j] * (wK[j] / 32) * (wN[j] / 32);
        if (blk < base + nb) break;
        base += nb;
        doff += (size_t)wL[j] * wK[j] * wN[j];
    }
    int rel = blk - base;
    int K = wK[j], N = wN[j];
    int tk = K / 32, tn = N / 32;
    int l = rel / (tk * tn); rel -= l * tk * tn;
    int kt = rel / tn, nt = rel - (rel / tn) * tn;
    const float* src = jobs.s[j] + (size_t)l * K * N;
    unsigned short* d = dst + doff + (size_t)l * K * N;
    __shared__ float tl[32][33];
    const int c = threadIdx.x & 31, rg = threadIdx.x >> 5;
#pragma unroll
    for (int rr = 0; rr < 4; rr++)
        tl[rg * 4 + rr][c] = src[(size_t)(kt * 32 + rg * 4 + rr) * N + nt * 32 + c];
    __syncthreads();
#pragma unroll
    for (int rr = 0; rr < 4; rr++)
        d[(size_t)(nt * 32 + rg * 4 + rr) * K + kt * 32 + c] = f2bf(tl[c][rg * 4 + rr]);
}

// ---------------------------------------------------------------- init h ----
__global__ __launch_bounds__(256) void init_h_k(const float* __restrict__ x,
                                                float* __restrict__ h)
{
    size_t idx = (size_t)blockIdx.x * 256 + threadIdx.x;   // kROWS*kDM
    int d  = idx & (kDM - 1);
    int t  = (idx >> 9) & (kN - 1);
    int bb = (int)(idx >> 19);
    int b = bb & 3, dir = bb >> 2;
    int ts = dir ? (kN - 1 - t) : t;
    h[idx] = x[((size_t)b * kN + ts) * kDM + d];
}

__global__ __launch_bounds__(256) void h2b_k(const float* __restrict__ h,
                                             unsigned short* __restrict__ o)
{
    size_t idx = (size_t)blockIdx.x * 256 + threadIdx.x;
    o[idx] = f2bf(h[idx]);
}

// ---------------------------------------------------------------- layernorm --
template<int DIM, int OBF>
__global__ __launch_bounds__(256) void ln_k(const float* __restrict__ x,
    const float* __restrict__ wf, const float* __restrict__ wb,
    const float* __restrict__ bf, const float* __restrict__ bbp,
    void* __restrict__ outv)
{
    const int row = blockIdx.x;
    const int tid = threadIdx.x;
    constexpr int PT = DIM / 256;
    const int dir = (row >= kMDIR) ? 1 : 0;
    const float* w = dir ? wb : wf;
    const float* b = dir ? bbp : bf;

    float v[PT];
    float s1 = 0.f, s2 = 0.f;
#pragma unroll
    for (int i = 0; i < PT; i++) {
        float t = x[(size_t)row * DIM + tid + i * 256];
        v[i] = t; s1 += t; s2 += t * t;
    }
    for (int o = 32; o > 0; o >>= 1) { s1 += __shfl_xor(s1, o, 64); s2 += __shfl_xor(s2, o, 64); }
    __shared__ float r1[4], r2[4];
    int wv = tid >> 6;
    if ((tid & 63) == 0) { r1[wv] = s1; r2[wv] = s2; }
    __syncthreads();
    s1 = r1[0] + r1[1] + r1[2] + r1[3];
    s2 = r2[0] + r2[1] + r2[2] + r2[3];
    float mu  = s1 / DIM;
    float var = s2 / DIM - mu * mu;
    float rr  = rsqrtf(var + 1e-5f);
#pragma unroll
    for (int i = 0; i < PT; i++) {
        int c = tid + i * 256;
        float o = (v[i] - mu) * rr * w[c] + b[c];
        if (OBF) ((unsigned short*)outv)[(size_t)row * DIM + c] = f2bf(o);
        else     ((float*)outv)[(size_t)row * DIM + c] = o;
    }
}

// ---------------------------------------------------------------- MFMA GEMM -
// C = A @ B (+bias)(+epilogue). A bf16 [M][lda], B^T bf16 [N][K].
// r20: K-loop REVERTED to the r18/r9 2-phase double-buffer (656us proven).
// r19's counted-vmcnt pipeline regressed (656->666): it needed TWO barriers
// per K-iter vs one, and at 4 waves/SIMD the TLP already covered most of
// the stall the counted wait targets (T4 pays inside an 8-phase schedule,
// not as a graft on a 1-phase loop -- guide's "null-as-graft" pattern).
template<int BM, int BN, int EPI, int ATR, int MODE, int OBF, int KB,
         int NTH = 256, int WSN = 2>
__global__ __launch_bounds__(NTH) void gemm_mfma(
    const unsigned short* __restrict__ A, int lda, int K,
    const unsigned short* __restrict__ Btf, const unsigned short* __restrict__ Btb,
    const float* __restrict__ biasf, const float* __restrict__ biasb,
    void* __restrict__ Cv, int ldc, unsigned short* __restrict__ Ct)
{
    constexpr int SK  = 40;              // padded LDS row stride (old path)
    constexpr int KT  = KB / 32;         // 32-wide sub-tiles per stage
    constexpr int CPR = KB / 8;          // 8-elem chunks per row (old path)
    constexpr int WAVES = NTH / 64;
    constexpr int WSM = WAVES / WSN;
    constexpr int WM  = BM / WSM, WN = BN / WSN;
    constexpr int MT  = WM / 16, NT = WN / 16;
    constexpr int ASL = (BM * KB) / (NTH * 8);
    constexpr int BSL = (BN * KB) / (NTH * 8);
    constexpr int ABUF = BM * 64;        // one K-tile of A (ushorts)
    constexpr int BBUF = BN * 64;
    constexpr int ASZ = (KB == 64) ? 2 * ABUF : KT * BM * SK;
    constexpr int BSZ = (KB == 64) ? 2 * BBUF : KT * BN * SK;

    __shared__ __align__(16) unsigned short As[ASZ];
    __shared__ __align__(16) unsigned short Bs[BSZ];

    const int tid  = threadIdx.x;
    // ---- XCD swizzle (T1, bijective: nwg % 8 == 0 for every launch here) --
    const int gx   = gridDim.x;
    const int nwg  = gx * gridDim.y;
    const int lin  = blockIdx.x + blockIdx.y * gx;
    const int swz  = (lin & 7) * (nwg >> 3) + (lin >> 3);
    const int by   = swz / gx;
    const int bx   = swz - by * gx;
    const int n0   = bx * BN;
    const int row0 = by * BM;
    const int dir  = (row0 >= kMDIR) ? 1 : 0;
    const unsigned short* __restrict__ Bt = dir ? Btb : Btf;
    const float* bias = dir ? biasb : biasf;

    const int lane = tid & 63;
    const int wave = tid >> 6;
    const int wr = wave / WSN, wc = wave % WSN;
    const int ml = lane & 15, q = lane >> 4;

    f32x4 acc[MT][NT];
#pragma unroll
    for (int i = 0; i < MT; i++)
#pragma unroll
        for (int j = 0; j < NT; j++)
#pragma unroll
            for (int r = 0; r < 4; r++) acc[i][j][r] = 0.f;

    if constexpr (KB == 64) {
        // ---- 2-phase double-buffered DMA K-loop (r18 structure) ----
        constexpr int ACW = (BM / 8) / WAVES;   // 1-KB chunks per wave (A)
        constexpr int BCW = (BN / 8) / WAVES;   // 1-KB chunks per wave (B)
        const int lrow = lane >> 3;                       // 0..7 row in chunk
        const int lcol = ((lane & 7) ^ (lrow & 7)) << 4;  // pre-swizzled col byte
        const char* aS[ACW ? ACW : 1];
        const char* bS[BCW ? BCW : 1];
#pragma unroll
        for (int ch = 0; ch < ACW; ch++) {
            const int chunk = wave * ACW + ch;
            aS[ch] = (const char*)A + (size_t)(row0 + chunk * 8 + lrow) * lda * 2 + lcol;
        }
#pragma unroll
        for (int ch = 0; ch < BCW; ch++) {
            const int chunk = wave * BCW + ch;
            bS[ch] = (const char*)Bt + (size_t)(n0 + chunk * 8 + lrow) * K * 2 + lcol;
        }
        const int axor = (ml & 7) << 3;  // read-side swizzle (ushort units)

        auto stage = [&](int buf) {
#pragma unroll
            for (int ch = 0; ch < ACW; ch++) {
                GLD_LDS16(aS[ch], &As[buf * ABUF + (wave * ACW + ch) * 512]);
                aS[ch] += 128;
            }
#pragma unroll
            for (int ch = 0; ch < BCW; ch++) {
                GLD_LDS16(bS[ch], &Bs[buf * BBUF + (wave * BCW + ch) * 512]);
                bS[ch] += 128;
            }
        };

        stage(0);
        __syncthreads();                 // buf0 staged (vmcnt(0) + barrier)
        const int NKT = K >> 6;
        int cur = 0;
        for (int t = 0; t < NKT; t++) {
            if (t + 1 < NKT) stage(cur ^ 1);   // prefetch BEFORE compute
#pragma unroll
            for (int kk = 0; kk < 2; kk++) {
                bf16x8 af[MT], bfr[NT];
#pragma unroll
                for (int i = 0; i < MT; i++)
                    af[i] = *(bf16x8*)&As[cur * ABUF + (wr * WM + i * 16 + ml) * 64 + ((kk * 32 + q * 8) ^ axor)];
#pragma unroll
                for (int j = 0; j < NT; j++)
                    bfr[j] = *(bf16x8*)&Bs[cur * BBUF + (wc * WN + j * 16 + ml) * 64 + ((kk * 32 + q * 8) ^ axor)];
#pragma unroll
                for (int i = 0; i < MT; i++)
#pragma unroll
                    for (int j = 0; j < NT; j++)
                        acc[i][j] = __builtin_amdgcn_mfma_f32_16x16x32_bf16(af[i], bfr[j], acc[i][j], 0, 0, 0);
            }
            __syncthreads();   // per-wave vmcnt(0): next buf staged; lgkm(0): cur reads done
            cur ^= 1;
        }
    } else {
        // ---- old reg-staging path (KB==32: dtw GEMM only, NTH==256) ----
        for (int kt = 0; kt < K; kt += KB) {
            bf16x8 a_ld[ASL ? ASL : 1];
#pragma unroll
            for (int r = 0; r < ASL; r++) {
                int i = tid + r * NTH;
                int m = i / CPR, c8 = (i % CPR) * 8;
                a_ld[r] = *(const bf16x8*)(A + (size_t)(row0 + m) * lda + kt + c8);
            }
            bf16x8 b_ld[BSL ? BSL : 1];
#pragma unroll
            for (int r = 0; r < BSL; r++) {
                int i = tid + r * NTH;
                int n = i / CPR, c8 = (i % CPR) * 8;
                b_ld[r] = *(const bf16x8*)(Bt + (size_t)(n0 + n) * K + kt + c8);
            }
            __syncthreads();
#pragma unroll
            for (int r = 0; r < ASL; r++) {
                int i = tid + r * NTH;
                int m = i / CPR, c8 = (i % CPR) * 8;
                *(bf16x8*)&As[((c8 >> 5) * BM + m) * SK + (c8 & 31)] = a_ld[r];
            }
#pragma unroll
            for (int r = 0; r < BSL; r++) {
                int i = tid + r * NTH;
                int n = i / CPR, c8 = (i % CPR) * 8;
                *(bf16x8*)&Bs[((c8 >> 5) * BN + n) * SK + (c8 & 31)] = b_ld[r];
            }
            __syncthreads();
#pragma unroll
            for (int kk = 0; kk < KT; kk++) {
                bf16x8 af[MT], bfr[NT];
#pragma unroll
                for (int i = 0; i < MT; i++)
                    af[i] = *(bf16x8*)&As[(kk * BM + wr * WM + i * 16 + ml) * SK + q * 8];
#pragma unroll
                for (int j = 0; j < NT; j++)
                    bfr[j] = *(bf16x8*)&Bs[(kk * BN + wc * WN + j * 16 + ml) * SK + q * 8];
#pragma unroll
                for (int i = 0; i < MT; i++)
#pragma unroll
                    for (int j = 0; j < NT; j++)
                        acc[i][j] = __builtin_amdgcn_mfma_f32_16x16x32_bf16(af[i], bfr[j], acc[i][j], 0, 0, 0);
            }
            __syncthreads();
        }
    }

    // ---- epilogue ----
    float* Cf = (float*)Cv;
    unsigned short* Cb = (unsigned short*)Cv;
#pragma unroll
    for (int j = 0; j < NT; j++) {
        int col = n0 + wc * WN + j * 16 + ml;
        float bv = 0.f;
        if (EPI == EPI_SOFTPLUS || EPI == EPI_GELU || EPI == EPI_RESID_BIAS || EPI == EPI_TANH)
            bv = bias[col];
#pragma unroll
        for (int i = 0; i < MT; i++) {
            int rw = row0 + wr * WM + i * 16 + q * 4;
            float v4[4];
#pragma unroll
            for (int r = 0; r < 4; r++) {
                float v = acc[i][j][r] + bv;
                if (EPI == EPI_SOFTPLUS) v = (v > 20.f) ? v : __logf(1.f + __expf(v));
                if (EPI == EPI_GELU)     v = 0.5f * v * (1.f + erf_as(v * 0.70710678118654752f));
                if (EPI == EPI_TANH)     v = tanhf(v);
                v4[r] = v;
            }
            if (MODE == MODE_GATE && n0 >= kDI) {
                // silu(z) -> gate row-major [row][kDI]
#pragma unroll
                for (int r = 0; r < 4; r++) {
                    float sv = v4[r] / (1.f + __expf(-v4[r]));
                    Ct[(size_t)(rw + r) * kDI + (col - kDI)] = f2bf(sv);
                }
            } else {
#pragma unroll
                for (int r = 0; r < 4; r++) {
                    size_t o = (size_t)(rw + r) * ldc + col;
                    if (EPI == EPI_RESID || EPI == EPI_RESID_BIAS) Cf[o] += v4[r];
                    else if (OBF) Cb[o] = f2bf(v4[r]);
                    else Cf[o] = v4[r];
                }
                if (MODE == MODE_DBL && col >= 32) {
                    float* F = (float*)Ct;          // dblF f32 [row][32]
#pragma unroll
                    for (int r = 0; r < 4; r++)
                        F[(size_t)(rw + r) * 32 + (col - 32)] = v4[r];
                }
            }
        }
    }
}

// ---------------------------------------------------------------- conv ------
// xb bf16 [row][kDI] (x-half) -> xh bf16 [row][kDI] = silu(causal conv + cb).
__global__ __launch_bounds__(256) void conv_k(const unsigned short* __restrict__ xb,
    const float* __restrict__ cwf, const float* __restrict__ cwb,
    const float* __restrict__ cbf, const float* __restrict__ cbb,
    unsigned short* __restrict__ xh)
{
    __shared__ float tl[67][33];
    const int t0 = blockIdx.x * 64, d0 = blockIdx.y * 32, bb = blockIdx.z;
    const int dir = bb >> 2;
    const float* cw = dir ? cwb : cwf;
    const float* cb = dir ? cbb : cbf;
    const int dl = threadIdx.x & 31, rl = threadIdx.x >> 5;
    const size_t base = (size_t)bb * kN * kDI + d0 + dl;
#pragma unroll
    for (int p = 0; p < 9; p++) {
        int r = p * 8 + rl;
        if (r < 67) {
            int ts = t0 + r - 3;
            tl[r][dl] = (ts >= 0) ? b2f(xb[base + (size_t)ts * kDI]) : 0.f;
        }
    }
    __syncthreads();
    const int gd = d0 + dl;
    float c0 = cw[gd*4+0], c1 = cw[gd*4+1], c2 = cw[gd*4+2], c3 = cw[gd*4+3];
    float bv = cb[gd];
#pragma unroll
    for (int jj = 0; jj < 8; jj++) {
        int tt = rl + 8 * jj;
        float acc = bv + c0*tl[tt][dl] + c1*tl[tt+1][dl] + c2*tl[tt+2][dl] + c3*tl[tt+3][dl];
        float o = acc / (1.f + __expf(-acc));
        xh[(size_t)(bb * kN + t0 + tt) * kDI + gd] = f2bf(o);
    }
}

// ---------------------------------------------------------------- scan ------
// r14 coalesced blocked scan + r20 PL-thinning: pass0 stores only L (16
// slots) + a per-(chain,group) sdt scalar (1 MB); bfix recomputes
// P = exp2(a2*sdt) on the fly (1 exp2 per (s,g) -- trivial in a BW-bound
// kernel). Saves ~16 MB write (pass0) + ~16 MB read (bfix) per layer.
// Arithmetic bit-identical (same exp2(a2*sdt), evaluated in bfix).
constexpr int kG  = 32;           // groups per chain
constexpr int kTg = kN / kG;      // 32 timesteps per group

template<int PASS>
__global__ __launch_bounds__(256) void bscan_k(
    const unsigned short* __restrict__ dt,   // [row][kDI]
    const unsigned short* __restrict__ xh,   // [row][kDI]
    const unsigned short* __restrict__ gate, // [row][kDI]
    const float* __restrict__ dblF,          // [row][32] (B | C)
    unsigned short* __restrict__ y,          // [row][kDI]
    float* __restrict__ PL,                  // [bb][g][16 L-slots][kDI]
    float* __restrict__ SDT,                 // [bb][g][kDI]
    const float* __restrict__ alogf, const float* __restrict__ alogb,
    const float* __restrict__ ddf,   const float* __restrict__ ddb)
{
    const int d  = blockIdx.x * 256 + threadIdx.x;   // 0..1023
    const int g  = blockIdx.y;                       // 0..31
    const int bb = blockIdx.z;                       // 0..7
    const int dir = bb >> 2;
    const float* alog = dir ? alogb : alogf;
    const float* ddp  = dir ? ddb  : ddf;

    float a2[16];
#pragma unroll
    for (int s = 0; s < 16; s += 4) {
        float4 al = *(const float4*)&alog[d * kDS + s];
        a2[s+0] = -__expf(al.x) * 1.44269504f;
        a2[s+1] = -__expf(al.y) * 1.44269504f;
        a2[s+2] = -__expf(al.z) * 1.44269504f;
        a2[s+3] = -__expf(al.w) * 1.44269504f;
    }

    const size_t plb = (size_t)(bb * kG + g) * 16 * kDI + d;   // L-slot stride kDI
    float h[16];
    if (PASS == 0) {
#pragma unroll
        for (int s = 0; s < 16; s++) h[s] = 0.f;
    } else {
#pragma unroll
        for (int s = 0; s < 16; s++) h[s] = PL[plb + (size_t)s * kDI];
    }

    const int row0 = bb * kN + g * kTg;
    const unsigned short* pd = dt   + (size_t)row0 * kDI + d;
    const unsigned short* px = xh   + (size_t)row0 * kDI + d;
    const unsigned short* pg = gate + (size_t)row0 * kDI + d;
    const float* pbc = dblF + (size_t)row0 * 32;
    unsigned short* py = y + (size_t)row0 * kDI + d;
    const float ddv = ddp[d];
    float sdt = 0.f;

#pragma unroll 4
    for (int t = 0; t < kTg; t++) {
        float dtv = b2f(pd[(size_t)t * kDI]);
        float xvv = b2f(px[(size_t)t * kDI]);
        float dtx = dtv * xvv;
        const float* bc = pbc + t * 32;
        if (PASS == 0) {
            sdt += dtv;
#pragma unroll
            for (int s4 = 0; s4 < 4; s4++) {
                float4 Bq = *(const float4*)(bc + s4 * 4);
                h[s4*4+0] = __builtin_amdgcn_exp2f(dtv * a2[s4*4+0]) * h[s4*4+0] + dtx * Bq.x;
                h[s4*4+1] = __builtin_amdgcn_exp2f(dtv * a2[s4*4+1]) * h[s4*4+1] + dtx * Bq.y;
                h[s4*4+2] = __builtin_amdgcn_exp2f(dtv * a2[s4*4+2]) * h[s4*4+2] + dtx * Bq.z;
                h[s4*4+3] = __builtin_amdgcn_exp2f(dtv * a2[s4*4+3]) * h[s4*4+3] + dtx * Bq.w;
            }
        } else {
            float p = 0.f;
#pragma unroll
            for (int s4 = 0; s4 < 4; s4++) {
                float4 Bq = *(const float4*)(bc + s4 * 4);
                float4 Cq = *(const float4*)(bc + 16 + s4 * 4);
                h[s4*4+0] = __builtin_amdgcn_exp2f(dtv * a2[s4*4+0]) * h[s4*4+0] + dtx * Bq.x;
                p += h[s4*4+0] * Cq.x;
                h[s4*4+1] = __builtin_amdgcn_exp2f(dtv * a2[s4*4+1]) * h[s4*4+1] + dtx * Bq.y;
                p += h[s4*4+1] * Cq.y;
                h[s4*4+2] = __builtin_amdgcn_exp2f(dtv * a2[s4*4+2]) * h[s4*4+2] + dtx * Bq.z;
                p += h[s4*4+2] * Cq.z;
                h[s4*4+3] = __builtin_amdgcn_exp2f(dtv * a2[s4*4+3]) * h[s4*4+3] + dtx * Bq.w;
                p += h[s4*4+3] * Cq.w;
            }
            float gvv = b2f(pg[(size_t)t * kDI]);
            py[(size_t)t * kDI] = f2bf((p + ddv * xvv) * gvv);
        }
    }

    if (PASS == 0) {
#pragma unroll
        for (int s = 0; s < 16; s++)
            PL[plb + (size_t)s * kDI] = h[s];
        SDT[(size_t)(bb * kG + g) * kDI + d] = sdt;
    }
}

// boundary fix: h_in[chain][g] = scan of (P,L) over groups; P recomputed
// from sdt (exp2(a2*sdt), bit-identical to pass0's former P store).
__global__ __launch_bounds__(256) void bfix_k(float* __restrict__ PL,
    const float* __restrict__ SDT,
    const float* __restrict__ alogf, const float* __restrict__ alogb)
{
    const int idx = blockIdx.x * 256 + threadIdx.x;  // 16 s x 8 bb x 1024 d
    const int d  = idx & (kDI - 1);
    const int bb = (idx >> 10) & 7;
    const int s  = idx >> 13;
    const int dir = bb >> 2;
    const float* alog = dir ? alogb : alogf;
    const float a2 = -__expf(alog[d * kDS + s]) * 1.44269504f;
    float h = 0.f;
    for (int g = 0; g < kG; g++) {
        size_t base = (size_t)(bb * kG + g) * 16 * kDI + d;
        float L = PL[base + (size_t)s * kDI];
        float P = __builtin_amdgcn_exp2f(a2 * SDT[(size_t)(bb * kG + g) * kDI + d]);
        PL[base + (size_t)s * kDI] = h;  // h_in for pass C
        h = P * h + L;
    }
}

// ---------------------------------------------------------------- attention -
__global__ __launch_bounds__(64) void att_score_k(const unsigned short* __restrict__ tmp,
    const float* __restrict__ aw2, const float* __restrict__ ab2,
    float* __restrict__ score)
{
    int row = blockIdx.x, lane = threadIdx.x;
    float acc = 0.f;
#pragma unroll
    for (int j = 0; j < 4; j++)
        acc += b2f(tmp[(size_t)row * 256 + lane + j * 64]) * aw2[lane + j * 64];
    for (int o = 32; o > 0; o >>= 1) acc += __shfl_xor(acc, o, 64);
    if (lane == 0) score[row] = acc + ab2[0];
}

__global__ __launch_bounds__(256) void softmax_k(const float* __restrict__ score,
                                                 float* __restrict__ w)
{
    int bb = blockIdx.x, tid = threadIdx.x;
    float v[4]; float m = -1e30f;
#pragma unroll
    for (int i = 0; i < 4; i++) { v[i] = score[bb * kN + tid + i * 256]; m = fmaxf(m, v[i]); }
    for (int o = 32; o > 0; o >>= 1) m = fmaxf(m, __shfl_xor(m, o, 64));
    __shared__ float r1[4], r2[4];
    int wv = tid >> 6;
    if ((tid & 63) == 0) r1[wv] = m;
    __syncthreads();
    m = fmaxf(fmaxf(r1[0], r1[1]), fmaxf(r1[2], r1[3]));
    float s = 0.f;
#pragma unroll
    for (int i = 0; i < 4; i++) { v[i] = __expf(v[i] - m); s += v[i]; }
    for (int o = 32; o > 0; o >>= 1) s += __shfl_xor(s, o, 64);
    if ((tid & 63) == 0) r2[wv] = s;
    __syncthreads();
    s = r2[0] + r2[1] + r2[2] + r2[3];
    float inv = 1.f / s;
#pragma unroll
    for (int i = 0; i < 4; i++) w[bb * kN + tid + i * 256] = v[i] * inv;
}

__global__ __launch_bounds__(512) void pool_k(const float* __restrict__ w,
    const float* __restrict__ h, float* zcat)
{
    int bb = blockIdx.x, chunk = blockIdx.y;   // 8 x 32
    int d = threadIdx.x;
    float acc = 0.f;
    int n0 = chunk * 32;
    for (int n = n0; n < n0 + 32; n++)
        acc += w[bb * kN + n] * h[((size_t)bb * kN + n) * kDM + d];
    int b = bb & 3, dir = bb >> 2;
    atomicAdd(&zcat[b * (2 * kDM) + dir * kDM + d], acc);
}

__global__ __launch_bounds__(256) void att_out_k(const float* __restrict__ w,
                                                 float* __restrict__ out)
{
    int idx = blockIdx.x * 256 + threadIdx.x;  // kB*kN
    int b = idx >> 10, n = idx & 1023;
    out[idx] = 0.5f * (w[b * kN + n] + w[(b + 4) * kN + (kN - 1 - n)]);
}

// ---------------------------------------------------------------- launch ----
extern "C" void kernel_launch(void* const* d_in, const int* in_sizes, int n_in,
                              void* d_out, int out_size, void* d_ws, size_t ws_size,
                              hipStream_t stream)
{
    const float* x = (const float*)d_in[0];
    const float* fp[17]; const float* bp[17];
    for (int i = 0; i < 17; i++) { fp[i] = (const float*)d_in[1 + i]; bp[i] = (const float*)d_in[18 + i]; }
    const float* aw1 = (const float*)d_in[35];
    const float* ab1 = (const float*)d_in[36];
    const float* aw2 = (const float*)d_in[37];
    const float* ab2 = (const float*)d_in[38];
    const float* nw  = (const float*)d_in[39];
    const float* nb  = (const float*)d_in[40];
    float* out = (float*)d_out;

    float* h = (float*)d_ws;                                   // 8192*512 f32
    unsigned short* ub    = (unsigned short*)(h + (size_t)kROWS * kDM);  // 8192*512
    unsigned short* xbuf  = ub    + (size_t)kROWS * kDM;        // 8192*1024 (x-half / y / ffn1 lo)
    unsigned short* tbuf  = xbuf  + (size_t)kROWS * kDI;        // 8192*1024 (dt / ffn1 hi / hb)
    unsigned short* xhb   = tbuf  + (size_t)kROWS * kDI;        // 8192*1024 (xh row-major)
    unsigned short* gateb = xhb   + (size_t)kROWS * kDI;        // 8192*1024 (gate row-major)
    unsigned short* dbl   = gateb + (size_t)kROWS * kDI;        // 8192*64 bf16
    float* dblF  = (float*)(dbl + (size_t)kROWS * 64);          // 8192*32 f32 (B/C)
    float* score = dblF + (size_t)kROWS * 32;                   // 8192
    float* smw   = score + kROWS;                               // 8192
    float* zcat  = smw   + kROWS;                               // 4096
    unsigned short* wts  = (unsigned short*)(zcat + kB * 2 * kDM);
    float* PL  = (float*)(wts + O_WTOT);                        // 8*32*16*1024 f32 = 16.8MB
    float* SDT = PL + (size_t)kB2 * kG * 16 * kDI;              // 8*32*1024 f32 = 1MB

    // ---- weight prep: fp32 [L][K][N] -> bf16 [L][N][K] (one launch) ----
    WJobs jobs;
    jobs.s[0] = fp[2];  jobs.s[1] = bp[2];
    jobs.s[2] = fp[5];  jobs.s[3] = bp[5];
    jobs.s[4] = fp[6];  jobs.s[5] = bp[6];
    jobs.s[6] = fp[10]; jobs.s[7] = bp[10];
    jobs.s[8] = fp[13]; jobs.s[9] = bp[13];
    jobs.s[10] = fp[15]; jobs.s[11] = bp[15];
    jobs.s[12] = aw1;
    int wblocks = 0;
    {
        const int wK[13] = {512,512,1024,1024,32,32,1024,1024,512,512,2048,2048,512};
        const int wN[13] = {2048,2048,64,64,1024,1024,512,512,2048,2048,512,512,256};
        const int wL[13] = {2,2,2,2,2,2,2,2,2,2,2,2,1};
        for (int j = 0; j < 13; j++) wblocks += wL[j] * (wK[j]/32) * (wN[j]/32);
    }
    wprep_k<<<wblocks, 256, 0, stream>>>(jobs, wts);

    init_h_k<<<kROWS * kDM / 256, 256, 0, stream>>>(x, h);

    for (int l = 0; l < kL; l++) {
        const float *f_n1w = fp[0]  + l * kDM,            *b_n1w = bp[0]  + l * kDM;
        const float *f_n1b = fp[1]  + l * kDM,            *b_n1b = bp[1]  + l * kDM;
        const float *f_cw  = fp[3]  + l * kDI * kDC,      *b_cw  = bp[3]  + l * kDI * kDC;
        const float *f_cb  = fp[4]  + l * kDI,            *b_cb  = bp[4]  + l * kDI;
        const float *f_dtb = fp[7]  + l * kDI,            *b_dtb = bp[7]  + l * kDI;
        const float *f_alog= fp[8]  + l * kDI * kDS,      *b_alog= bp[8]  + l * kDI * kDS;
        const float *f_dd  = fp[9]  + l * kDI,            *b_dd  = bp[9]  + l * kDI;
        const float *f_n2w = fp[11] + l * kDM,            *b_n2w = bp[11] + l * kDM;
        const float *f_n2b = fp[12] + l * kDM,            *b_n2b = bp[12] + l * kDM;
        const float *f_b1  = fp[14] + l * 4 * kDM,        *b_b1  = bp[14] + l * 4 * kDM;
        const float *f_b2  = fp[16] + l * kDM,            *b_b2  = bp[16] + l * kDM;

        const unsigned short *wInwF = wts + O_INW_F + (size_t)l * 2048 * 512;
        const unsigned short *wInwB = wts + O_INW_B + (size_t)l * 2048 * 512;
        const unsigned short *wXpwF = wts + O_XPW_F + (size_t)l * 64 * 1024;
        const unsigned short *wXpwB = wts + O_XPW_B + (size_t)l * 64 * 1024;
        const unsigned short *wDtwF = wts + O_DTW_F + (size_t)l * 1024 * 32;
        const unsigned short *wDtwB = wts + O_DTW_B + (size_t)l * 1024 * 32;
        const unsigned short *wOwF  = wts + O_OW_F  + (size_t)l * 512 * 1024;
        const unsigned short *wOwB  = wts + O_OW_B  + (size_t)l * 512 * 1024;
        const unsigned short *wW1F  = wts + O_W1_F  + (size_t)l * 2048 * 512;
        const unsigned short *wW1B  = wts + O_W1_B  + (size_t)l * 2048 * 512;
        const unsigned short *wW2F  = wts + O_W2_F  + (size_t)l * 512 * 2048;
        const unsigned short *wW2B  = wts + O_W2_B  + (size_t)l * 512 * 2048;

        // u = LN1(h) -> bf16
        ln_k<kDM,1><<<kROWS, 256, 0, stream>>>(h, f_n1w, b_n1w, f_n1b, b_n1b, ub);
        // x-half -> xbuf bf16 [row][kDI]; z-half -> gateb = silu(z) row-major
        // 512-thread / 8-wave blocks (2M x 4N): 4 waves/SIMD at 2 blocks/CU
        gemm_mfma<128,128,EPI_NONE,0,MODE_GATE,1,64,512,4><<<dim3(16, 64), 512, 0, stream>>>(
            ub, kDM, kDM, wInwF, wInwB, nullptr, nullptr, xbuf, kDI, gateb);
        // xh[row][kDI] = silu(conv(xbuf) + cb)  (row-major, no transpose)
        conv_k<<<dim3(kN/64, kDI/32, kB2), 256, 0, stream>>>(
            xbuf, f_cw, b_cw, f_cb, b_cb, xhb);
        // dbl = xh @ xpw (A row-major); cols>=32 also -> dblF f32 [row][32]
        gemm_mfma<32,64,EPI_NONE,0,MODE_DBL,1,64><<<dim3(1, 256), 256, 0, stream>>>(
            xhb, kDI, kDI, wXpwF, wXpwB, nullptr, nullptr, dbl, 64, (unsigned short*)dblF);
        // dt[row][kDI] = softplus(dbl[:, :32] @ dtw + dtb)  (row-major)
        gemm_mfma<128,128,EPI_SOFTPLUS,0,MODE_N,1,32><<<dim3(8, 64), 256, 0, stream>>>(
            dbl, 64, kDTR, wDtwF, wDtwB, f_dtb, b_dtb, tbuf, kDI, nullptr);
        // blocked scan: local pass -> boundary fix -> full pass (y into xbuf)
        bscan_k<0><<<dim3(kDI/256, kG, kB2), 256, 0, stream>>>(
            tbuf, xhb, gateb, dblF, xbuf, PL, SDT, f_alog, b_alog, f_dd, b_dd);
        bfix_k<<<kB2 * kDI * kDS / 256, 256, 0, stream>>>(PL, SDT, f_alog, b_alog);
        bscan_k<1><<<dim3(kDI/256, kG, kB2), 256, 0, stream>>>(
            tbuf, xhb, gateb, dblF, xbuf, PL, SDT, f_alog, b_alog, f_dd, b_dd);
        // h += y @ ow  (512-thread / 8-wave blocks, 4M x 2N)
        gemm_mfma<128,64,EPI_RESID,0,MODE_N,0,64,512,2><<<dim3(8, 64), 512, 0, stream>>>(
            xbuf, kDI, kDI, wOwF, wOwB, nullptr, nullptr, h, kDM, nullptr);
        // u = LN2(h) -> bf16
        ln_k<kDM,1><<<kROWS, 256, 0, stream>>>(h, f_n2w, b_n2w, f_n2b, b_n2b, ub);
        // ffn1: gelu(u @ w1 + b1) -> xbuf..tbuf slab bf16 (8192 x 2048)
        gemm_mfma<128,128,EPI_GELU,0,MODE_N,1,64,512,4><<<dim3(16, 64), 512, 0, stream>>>(
            ub, kDM, kDM, wW1F, wW1B, f_b1, b_b1, xbuf, 4*kDM, nullptr);
        // h += ffn1 @ w2 + b2  (512-thread / 8-wave blocks, 4M x 2N)
        gemm_mfma<128,64,EPI_RESID_BIAS,0,MODE_N,0,64,512,2><<<dim3(8, 64), 512, 0, stream>>>(
            xbuf, 4*kDM, 4*kDM, wW2F, wW2B, f_b2, b_b2, h, kDM, nullptr);
    }

    // attention: hb = bf16(h); u = tanh(hb @ aw1 + ab1) bf16
    h2b_k<<<kROWS * kDM / 256, 256, 0, stream>>>(h, tbuf);
    // 64x128 tile -> 256 blocks
    gemm_mfma<64,128,EPI_TANH,0,MODE_N,1,64><<<dim3(2, 128), 256, 0, stream>>>(
        tbuf, kDM, kDM, wts + O_AW1, wts + O_AW1, ab1, ab1, ub, 256, nullptr);
    att_score_k<<<kROWS, 64, 0, stream>>>(ub, aw2, ab2, score);
    softmax_k<<<kB2, 256, 0, stream>>>(score, smw);
    hipMemsetAsync(zcat, 0, kB * 2 * kDM * sizeof(float), stream);
    pool_k<<<dim3(kB2, 32), 512, 0, stream>>>(smw, h, zcat);
    // out[0:4096] = LN(concat(zf, zb))
    ln_k<2*kDM,0><<<kB, 256, 0, stream>>>(zcat, nw, nw, nb, nb, out);
    // out[4096:8192] = 0.5*(af + flip(ab))
    att_out_k<<<kB * kN / 256, 256, 0, stream>>>(smw, out + kB * 2 * kDM);
}

// Round 12
// 641.823 us; speedup vs baseline: 1.0386x; 1.0138x over previous
//
#include <hip/hip_runtime.h>
#include <math.h>

constexpr int kDM   = 512;
constexpr int kDI   = 1024;
constexpr int kDS   = 16;
constexpr int kDC   = 4;
constexpr int kDTR  = 32;
constexpr int kL    = 2;
constexpr int kB    = 4;
constexpr int kN    = 1024;
constexpr int kB2   = 8;              // combined batch: rows 0-3 fwd, 4-7 bwd
constexpr int kROWS = kB2 * kN;       // 8192
constexpr int kMDIR = kB * kN;        // 4096 rows per direction

enum { EPI_NONE=0, EPI_SOFTPLUS=1, EPI_RESID=2, EPI_GELU=3, EPI_RESID_BIAS=4, EPI_TANH=5 };
enum { MODE_N=0, MODE_OTR=1, MODE_DBL=2, MODE_GATE=3, MODE_RESB16=4 };

typedef __attribute__((ext_vector_type(8))) short bf16x8;
typedef __attribute__((ext_vector_type(4))) short bf16x4;
typedef __attribute__((ext_vector_type(4))) float f32x4;

__device__ __forceinline__ unsigned short f2bf(float f) {
    unsigned int u = __float_as_uint(f);
    return (unsigned short)((u + 0x7FFFu + ((u >> 16) & 1u)) >> 16);
}
__device__ __forceinline__ float b2f(unsigned short u) {
    return __uint_as_float((unsigned int)u << 16);
}

// Abramowitz-Stegun 7.1.26 erf: max err 1.5e-7 (+ ~1e-7 from v_rcp) --
// far below bf16 LSB (2^-8 rel), replaces branchy libm erff (~50 inst -> ~14).
__device__ __forceinline__ float erf_as(float x) {
    float ax = fabsf(x);
    float t  = __builtin_amdgcn_rcpf(1.f + 0.3275911f * ax);
    float p  = t * (0.254829592f + t * (-0.284496736f + t * (1.421413741f +
               t * (-1.453152027f + t * 1.061405429f))));
    float e  = __builtin_amdgcn_exp2f(ax * ax * -1.44269504f);
    float r  = 1.f - p * e;
    return __builtin_copysignf(r, x);
}

// global -> LDS 16-B DMA (one instruction, no VGPR round-trip)
#define GLD_LDS16(gsrc, ldst) \
    __builtin_amdgcn_global_load_lds((const __attribute__((address_space(1))) void*)(gsrc), \
                                     (__attribute__((address_space(3))) void*)(ldst), 16, 0, 0)

// ------------------------------------------------------- weight prep --------
struct WJobs { const float* s[13]; };
// job order: f_inw b_inw f_xpw b_xpw f_dtw b_dtw f_ow b_ow f_w1 b_w1 f_w2 b_w2 aw1
constexpr size_t O_INW_F = 0;
constexpr size_t O_INW_B = O_INW_F + 2u*512*2048;
constexpr size_t O_XPW_F = O_INW_B + 2u*512*2048;
constexpr size_t O_XPW_B = O_XPW_F + 2u*1024*64;
constexpr size_t O_DTW_F = O_XPW_B + 2u*1024*64;
constexpr size_t O_DTW_B = O_DTW_F + 2u*32*1024;
constexpr size_t O_OW_F  = O_DTW_B + 2u*32*1024;
constexpr size_t O_OW_B  = O_OW_F  + 2u*1024*512;
constexpr size_t O_W1_F  = O_OW_B  + 2u*1024*512;
constexpr size_t O_W1_B  = O_W1_F  + 2u*512*2048;
constexpr size_t O_W2_F  = O_W1_B  + 2u*512*2048;
constexpr size_t O_W2_B  = O_W2_F  + 2u*2048*512;
constexpr size_t O_AW1   = O_W2_B  + 2u*2048*512;
constexpr size_t O_WTOT  = O_AW1   + 1u*512*256;

__global__ __launch_bounds__(256) void wprep_k(WJobs jobs, unsigned short* __restrict__ dst)
{
    const int wK[13] = {512,512,1024,1024,32,32,1024,1024,512,512,2048,2048,512};
    const int wN[13] = {2048,2048,64,64,1024,1024,512,512,2048,2048,512,512,256};
    const int wL[13] = {2,2,2,2,2,2,2,2,2,2,2,2,1};
    int blk = blockIdx.x;
    int j = 0; int base = 0; size_t doff = 0;
    for (; j < 13; j++) {
        int nb = wL[j] * (wK[j] / 32) * (wN[j] / 32);
        if (blk < base + nb) break;
        base += nb;
        doff += (size_t)wL[j] * wK[j] * wN[j];
    }
    int rel = blk - base;
    int K = wK[j], N = wN[j];
    int tk = K / 32, tn = N / 32;
    int l = rel / (tk * tn); rel -= l * tk * tn;
    int kt = rel / tn, nt = rel - (rel / tn) * tn;
    const float* src = jobs.s[j] + (size_t)l * K * N;
    unsigned short* d = dst + doff + (size_t)l * K * N;
    __shared__ float tl[32][33];
    const int c = threadIdx.x & 31, rg = threadIdx.x >> 5;
#pragma unroll
    for (int rr = 0; rr < 4; rr++)
        tl[rg * 4 + rr][c] = src[(size_t)(kt * 32 + rg * 4 + rr) * N + nt * 32 + c];
    __syncthreads();
#pragma unroll
    for (int rr = 0; rr < 4; rr++)
        d[(size_t)(nt * 32 + rg * 4 + rr) * K + kt * 32 + c] = f2bf(tl[c][rg * 4 + rr]);
}

// ---------------------------------------------------------------- init h ----
__global__ __launch_bounds__(256) void init_h_k(const float* __restrict__ x,
                                                float* __restrict__ h)
{
    size_t idx = (size_t)blockIdx.x * 256 + threadIdx.x;   // kROWS*kDM
    int d  = idx & (kDM - 1);
    int t  = (idx >> 9) & (kN - 1);
    int bb = (int)(idx >> 19);
    int b = bb & 3, dir = bb >> 2;
    int ts = dir ? (kN - 1 - t) : t;
    h[idx] = x[((size_t)b * kN + ts) * kDM + d];
}

// ---------------------------------------------------------------- layernorm --
template<int DIM, int OBF>
__global__ __launch_bounds__(256) void ln_k(const float* __restrict__ x,
    const float* __restrict__ wf, const float* __restrict__ wb,
    const float* __restrict__ bf, const float* __restrict__ bbp,
    void* __restrict__ outv)
{
    const int row = blockIdx.x;
    const int tid = threadIdx.x;
    constexpr int PT = DIM / 256;
    const int dir = (row >= kMDIR) ? 1 : 0;
    const float* w = dir ? wb : wf;
    const float* b = dir ? bbp : bf;

    float v[PT];
    float s1 = 0.f, s2 = 0.f;
#pragma unroll
    for (int i = 0; i < PT; i++) {
        float t = x[(size_t)row * DIM + tid + i * 256];
        v[i] = t; s1 += t; s2 += t * t;
    }
    for (int o = 32; o > 0; o >>= 1) { s1 += __shfl_xor(s1, o, 64); s2 += __shfl_xor(s2, o, 64); }
    __shared__ float r1[4], r2[4];
    int wv = tid >> 6;
    if ((tid & 63) == 0) { r1[wv] = s1; r2[wv] = s2; }
    __syncthreads();
    s1 = r1[0] + r1[1] + r1[2] + r1[3];
    s2 = r2[0] + r2[1] + r2[2] + r2[3];
    float mu  = s1 / DIM;
    float var = s2 / DIM - mu * mu;
    float rr  = rsqrtf(var + 1e-5f);
#pragma unroll
    for (int i = 0; i < PT; i++) {
        int c = tid + i * 256;
        float o = (v[i] - mu) * rr * w[c] + b[c];
        if (OBF) ((unsigned short*)outv)[(size_t)row * DIM + c] = f2bf(o);
        else     ((float*)outv)[(size_t)row * DIM + c] = o;
    }
}

// ---------------------------------------------------------------- MFMA GEMM -
// C = A @ B (+bias)(+epilogue). A bf16 [M][lda], B^T bf16 [N][K].
// KB==64: r18/r9 2-phase double-buffer DMA K-loop (proven 656us; r19's
// counted-vmcnt graft regressed -- needed 2 barriers/iter, and 4 waves/SIMD
// TLP already covers the stall it targets).
// r21: MODE_RESB16 -- RESID_BIAS epilogue also emits the updated h as bf16
// (replaces the separate h2b_k pass; same f2bf of the same float).
template<int BM, int BN, int EPI, int ATR, int MODE, int OBF, int KB,
         int NTH = 256, int WSN = 2>
__global__ __launch_bounds__(NTH) void gemm_mfma(
    const unsigned short* __restrict__ A, int lda, int K,
    const unsigned short* __restrict__ Btf, const unsigned short* __restrict__ Btb,
    const float* __restrict__ biasf, const float* __restrict__ biasb,
    void* __restrict__ Cv, int ldc, unsigned short* __restrict__ Ct)
{
    constexpr int SK  = 40;              // padded LDS row stride (old path)
    constexpr int KT  = KB / 32;         // 32-wide sub-tiles per stage
    constexpr int CPR = KB / 8;          // 8-elem chunks per row (old path)
    constexpr int WAVES = NTH / 64;
    constexpr int WSM = WAVES / WSN;
    constexpr int WM  = BM / WSM, WN = BN / WSN;
    constexpr int MT  = WM / 16, NT = WN / 16;
    constexpr int ASL = (BM * KB) / (NTH * 8);
    constexpr int BSL = (BN * KB) / (NTH * 8);
    constexpr int ABUF = BM * 64;        // one K-tile of A (ushorts)
    constexpr int BBUF = BN * 64;
    constexpr int ASZ = (KB == 64) ? 2 * ABUF : KT * BM * SK;
    constexpr int BSZ = (KB == 64) ? 2 * BBUF : KT * BN * SK;

    __shared__ __align__(16) unsigned short As[ASZ];
    __shared__ __align__(16) unsigned short Bs[BSZ];

    const int tid  = threadIdx.x;
    // ---- XCD swizzle (T1, bijective: nwg % 8 == 0 for every launch here) --
    const int gx   = gridDim.x;
    const int nwg  = gx * gridDim.y;
    const int lin  = blockIdx.x + blockIdx.y * gx;
    const int swz  = (lin & 7) * (nwg >> 3) + (lin >> 3);
    const int by   = swz / gx;
    const int bx   = swz - by * gx;
    const int n0   = bx * BN;
    const int row0 = by * BM;
    const int dir  = (row0 >= kMDIR) ? 1 : 0;
    const unsigned short* __restrict__ Bt = dir ? Btb : Btf;
    const float* bias = dir ? biasb : biasf;

    const int lane = tid & 63;
    const int wave = tid >> 6;
    const int wr = wave / WSN, wc = wave % WSN;
    const int ml = lane & 15, q = lane >> 4;

    f32x4 acc[MT][NT];
#pragma unroll
    for (int i = 0; i < MT; i++)
#pragma unroll
        for (int j = 0; j < NT; j++)
#pragma unroll
            for (int r = 0; r < 4; r++) acc[i][j][r] = 0.f;

    if constexpr (KB == 64) {
        // ---- 2-phase double-buffered DMA K-loop (r18 structure) ----
        constexpr int ACW = (BM / 8) / WAVES;   // 1-KB chunks per wave (A)
        constexpr int BCW = (BN / 8) / WAVES;   // 1-KB chunks per wave (B)
        const int lrow = lane >> 3;                       // 0..7 row in chunk
        const int lcol = ((lane & 7) ^ (lrow & 7)) << 4;  // pre-swizzled col byte
        const char* aS[ACW ? ACW : 1];
        const char* bS[BCW ? BCW : 1];
#pragma unroll
        for (int ch = 0; ch < ACW; ch++) {
            const int chunk = wave * ACW + ch;
            aS[ch] = (const char*)A + (size_t)(row0 + chunk * 8 + lrow) * lda * 2 + lcol;
        }
#pragma unroll
        for (int ch = 0; ch < BCW; ch++) {
            const int chunk = wave * BCW + ch;
            bS[ch] = (const char*)Bt + (size_t)(n0 + chunk * 8 + lrow) * K * 2 + lcol;
        }
        const int axor = (ml & 7) << 3;  // read-side swizzle (ushort units)

        auto stage = [&](int buf) {
#pragma unroll
            for (int ch = 0; ch < ACW; ch++) {
                GLD_LDS16(aS[ch], &As[buf * ABUF + (wave * ACW + ch) * 512]);
                aS[ch] += 128;
            }
#pragma unroll
            for (int ch = 0; ch < BCW; ch++) {
                GLD_LDS16(bS[ch], &Bs[buf * BBUF + (wave * BCW + ch) * 512]);
                bS[ch] += 128;
            }
        };

        stage(0);
        __syncthreads();                 // buf0 staged (vmcnt(0) + barrier)
        const int NKT = K >> 6;
        int cur = 0;
        for (int t = 0; t < NKT; t++) {
            if (t + 1 < NKT) stage(cur ^ 1);   // prefetch BEFORE compute
#pragma unroll
            for (int kk = 0; kk < 2; kk++) {
                bf16x8 af[MT], bfr[NT];
#pragma unroll
                for (int i = 0; i < MT; i++)
                    af[i] = *(bf16x8*)&As[cur * ABUF + (wr * WM + i * 16 + ml) * 64 + ((kk * 32 + q * 8) ^ axor)];
#pragma unroll
                for (int j = 0; j < NT; j++)
                    bfr[j] = *(bf16x8*)&Bs[cur * BBUF + (wc * WN + j * 16 + ml) * 64 + ((kk * 32 + q * 8) ^ axor)];
#pragma unroll
                for (int i = 0; i < MT; i++)
#pragma unroll
                    for (int j = 0; j < NT; j++)
                        acc[i][j] = __builtin_amdgcn_mfma_f32_16x16x32_bf16(af[i], bfr[j], acc[i][j], 0, 0, 0);
            }
            __syncthreads();   // per-wave vmcnt(0): next buf staged; lgkm(0): cur reads done
            cur ^= 1;
        }
    } else {
        // ---- old reg-staging path (KB==32: dtw GEMM only, NTH==256) ----
        for (int kt = 0; kt < K; kt += KB) {
            bf16x8 a_ld[ASL ? ASL : 1];
#pragma unroll
            for (int r = 0; r < ASL; r++) {
                int i = tid + r * NTH;
                int m = i / CPR, c8 = (i % CPR) * 8;
                a_ld[r] = *(const bf16x8*)(A + (size_t)(row0 + m) * lda + kt + c8);
            }
            bf16x8 b_ld[BSL ? BSL : 1];
#pragma unroll
            for (int r = 0; r < BSL; r++) {
                int i = tid + r * NTH;
                int n = i / CPR, c8 = (i % CPR) * 8;
                b_ld[r] = *(const bf16x8*)(Bt + (size_t)(n0 + n) * K + kt + c8);
            }
            __syncthreads();
#pragma unroll
            for (int r = 0; r < ASL; r++) {
                int i = tid + r * NTH;
                int m = i / CPR, c8 = (i % CPR) * 8;
                *(bf16x8*)&As[((c8 >> 5) * BM + m) * SK + (c8 & 31)] = a_ld[r];
            }
#pragma unroll
            for (int r = 0; r < BSL; r++) {
                int i = tid + r * NTH;
                int n = i / CPR, c8 = (i % CPR) * 8;
                *(bf16x8*)&Bs[((c8 >> 5) * BN + n) * SK + (c8 & 31)] = b_ld[r];
            }
            __syncthreads();
#pragma unroll
            for (int kk = 0; kk < KT; kk++) {
                bf16x8 af[MT], bfr[NT];
#pragma unroll
                for (int i = 0; i < MT; i++)
                    af[i] = *(bf16x8*)&As[(kk * BM + wr * WM + i * 16 + ml) * SK + q * 8];
#pragma unroll
                for (int j = 0; j < NT; j++)
                    bfr[j] = *(bf16x8*)&Bs[(kk * BN + wc * WN + j * 16 + ml) * SK + q * 8];
#pragma unroll
                for (int i = 0; i < MT; i++)
#pragma unroll
                    for (int j = 0; j < NT; j++)
                        acc[i][j] = __builtin_amdgcn_mfma_f32_16x16x32_bf16(af[i], bfr[j], acc[i][j], 0, 0, 0);
            }
            __syncthreads();
        }
    }

    // ---- epilogue ----
    float* Cf = (float*)Cv;
    unsigned short* Cb = (unsigned short*)Cv;
#pragma unroll
    for (int j = 0; j < NT; j++) {
        int col = n0 + wc * WN + j * 16 + ml;
        float bv = 0.f;
        if (EPI == EPI_SOFTPLUS || EPI == EPI_GELU || EPI == EPI_RESID_BIAS || EPI == EPI_TANH)
            bv = bias[col];
#pragma unroll
        for (int i = 0; i < MT; i++) {
            int rw = row0 + wr * WM + i * 16 + q * 4;
            float v4[4];
#pragma unroll
            for (int r = 0; r < 4; r++) {
                float v = acc[i][j][r] + bv;
                if (EPI == EPI_SOFTPLUS) v = (v > 20.f) ? v : __logf(1.f + __expf(v));
                if (EPI == EPI_GELU)     v = 0.5f * v * (1.f + erf_as(v * 0.70710678118654752f));
                if (EPI == EPI_TANH)     v = tanhf(v);
                v4[r] = v;
            }
            if (MODE == MODE_GATE && n0 >= kDI) {
                // silu(z) -> gate row-major [row][kDI]
#pragma unroll
                for (int r = 0; r < 4; r++) {
                    float sv = v4[r] / (1.f + __expf(-v4[r]));
                    Ct[(size_t)(rw + r) * kDI + (col - kDI)] = f2bf(sv);
                }
            } else {
#pragma unroll
                for (int r = 0; r < 4; r++) {
                    size_t o = (size_t)(rw + r) * ldc + col;
                    if (EPI == EPI_RESID || EPI == EPI_RESID_BIAS) {
                        float nv = Cf[o] + v4[r];
                        Cf[o] = nv;
                        if (MODE == MODE_RESB16) Ct[o] = f2bf(nv);   // fused h->bf16
                    }
                    else if (OBF) Cb[o] = f2bf(v4[r]);
                    else Cf[o] = v4[r];
                }
                if (MODE == MODE_DBL && col >= 32) {
                    float* F = (float*)Ct;          // dblF f32 [row][32]
#pragma unroll
                    for (int r = 0; r < 4; r++)
                        F[(size_t)(rw + r) * 32 + (col - 32)] = v4[r];
                }
            }
        }
    }
}

// ---------------------------------------------------------------- conv ------
// xb bf16 [row][kDI] (x-half) -> xh bf16 [row][kDI] = silu(causal conv + cb).
// r21: 2-wide vectorized (uint = 2 bf16 per load/store; 64-d blocks, grid
// halved). Same per-element arithmetic as the scalar version.
__global__ __launch_bounds__(256) void conv_k(const unsigned short* __restrict__ xb,
    const float* __restrict__ cwf, const float* __restrict__ cwb,
    const float* __restrict__ cbf, const float* __restrict__ cbb,
    unsigned short* __restrict__ xh)
{
    __shared__ float tl[67][66];
    const int t0 = blockIdx.x * 64, d0 = blockIdx.y * 64, bb = blockIdx.z;
    const int dir = bb >> 2;
    const float* cw = dir ? cwb : cwf;
    const float* cb = dir ? cbb : cbf;
    const int dl = (threadIdx.x & 31) * 2, rl = threadIdx.x >> 5;
    const size_t base = (size_t)bb * kN * kDI + d0 + dl;
#pragma unroll
    for (int p = 0; p < 9; p++) {
        int r = p * 8 + rl;
        if (r < 67) {
            int ts = t0 + r - 3;
            unsigned int u = (ts >= 0) ? *(const unsigned int*)(xb + base + (size_t)ts * kDI) : 0u;
            tl[r][dl]     = __uint_as_float(u << 16);
            tl[r][dl + 1] = __uint_as_float(u & 0xffff0000u);
        }
    }
    __syncthreads();
    const int g0 = d0 + dl;
    float c00 = cw[g0*4+0], c01 = cw[g0*4+1], c02 = cw[g0*4+2], c03 = cw[g0*4+3];
    float c10 = cw[g0*4+4], c11 = cw[g0*4+5], c12 = cw[g0*4+6], c13 = cw[g0*4+7];
    float bv0 = cb[g0], bv1 = cb[g0 + 1];
#pragma unroll
    for (int jj = 0; jj < 8; jj++) {
        int tt = rl + 8 * jj;
        float a0 = bv0 + c00*tl[tt][dl]   + c01*tl[tt+1][dl]   + c02*tl[tt+2][dl]   + c03*tl[tt+3][dl];
        float a1 = bv1 + c10*tl[tt][dl+1] + c11*tl[tt+1][dl+1] + c12*tl[tt+2][dl+1] + c13*tl[tt+3][dl+1];
        float o0 = a0 / (1.f + __expf(-a0));
        float o1 = a1 / (1.f + __expf(-a1));
        unsigned int w = (unsigned int)f2bf(o0) | ((unsigned int)f2bf(o1) << 16);
        *(unsigned int*)(xh + (size_t)(bb * kN + t0 + tt) * kDI + g0) = w;
    }
}

// ---------------------------------------------------------------- scan ------
// r14 coalesced blocked scan + r20 PL-thinning: pass0 stores only L (16
// slots) + a per-(chain,group) sdt scalar; bfix recomputes P = exp2(a2*sdt).
constexpr int kG  = 32;           // groups per chain
constexpr int kTg = kN / kG;      // 32 timesteps per group

template<int PASS>
__global__ __launch_bounds__(256) void bscan_k(
    const unsigned short* __restrict__ dt,   // [row][kDI]
    const unsigned short* __restrict__ xh,   // [row][kDI]
    const unsigned short* __restrict__ gate, // [row][kDI]
    const float* __restrict__ dblF,          // [row][32] (B | C)
    unsigned short* __restrict__ y,          // [row][kDI]
    float* __restrict__ PL,                  // [bb][g][16 L-slots][kDI]
    float* __restrict__ SDT,                 // [bb][g][kDI]
    const float* __restrict__ alogf, const float* __restrict__ alogb,
    const float* __restrict__ ddf,   const float* __restrict__ ddb)
{
    const int d  = blockIdx.x * 256 + threadIdx.x;   // 0..1023
    const int g  = blockIdx.y;                       // 0..31
    const int bb = blockIdx.z;                       // 0..7
    const int dir = bb >> 2;
    const float* alog = dir ? alogb : alogf;
    const float* ddp  = dir ? ddb  : ddf;

    float a2[16];
#pragma unroll
    for (int s = 0; s < 16; s += 4) {
        float4 al = *(const float4*)&alog[d * kDS + s];
        a2[s+0] = -__expf(al.x) * 1.44269504f;
        a2[s+1] = -__expf(al.y) * 1.44269504f;
        a2[s+2] = -__expf(al.z) * 1.44269504f;
        a2[s+3] = -__expf(al.w) * 1.44269504f;
    }

    const size_t plb = (size_t)(bb * kG + g) * 16 * kDI + d;   // L-slot stride kDI
    float h[16];
    if (PASS == 0) {
#pragma unroll
        for (int s = 0; s < 16; s++) h[s] = 0.f;
    } else {
#pragma unroll
        for (int s = 0; s < 16; s++) h[s] = PL[plb + (size_t)s * kDI];
    }

    const int row0 = bb * kN + g * kTg;
    const unsigned short* pd = dt   + (size_t)row0 * kDI + d;
    const unsigned short* px = xh   + (size_t)row0 * kDI + d;
    const unsigned short* pg = gate + (size_t)row0 * kDI + d;
    const float* pbc = dblF + (size_t)row0 * 32;
    unsigned short* py = y + (size_t)row0 * kDI + d;
    const float ddv = ddp[d];
    float sdt = 0.f;

#pragma unroll 4
    for (int t = 0; t < kTg; t++) {
        float dtv = b2f(pd[(size_t)t * kDI]);
        float xvv = b2f(px[(size_t)t * kDI]);
        float dtx = dtv * xvv;
        const float* bc = pbc + t * 32;
        if (PASS == 0) {
            sdt += dtv;
#pragma unroll
            for (int s4 = 0; s4 < 4; s4++) {
                float4 Bq = *(const float4*)(bc + s4 * 4);
                h[s4*4+0] = __builtin_amdgcn_exp2f(dtv * a2[s4*4+0]) * h[s4*4+0] + dtx * Bq.x;
                h[s4*4+1] = __builtin_amdgcn_exp2f(dtv * a2[s4*4+1]) * h[s4*4+1] + dtx * Bq.y;
                h[s4*4+2] = __builtin_amdgcn_exp2f(dtv * a2[s4*4+2]) * h[s4*4+2] + dtx * Bq.z;
                h[s4*4+3] = __builtin_amdgcn_exp2f(dtv * a2[s4*4+3]) * h[s4*4+3] + dtx * Bq.w;
            }
        } else {
            float p = 0.f;
#pragma unroll
            for (int s4 = 0; s4 < 4; s4++) {
                float4 Bq = *(const float4*)(bc + s4 * 4);
                float4 Cq = *(const float4*)(bc + 16 + s4 * 4);
                h[s4*4+0] = __builtin_amdgcn_exp2f(dtv * a2[s4*4+0]) * h[s4*4+0] + dtx * Bq.x;
                p += h[s4*4+0] * Cq.x;
                h[s4*4+1] = __builtin_amdgcn_exp2f(dtv * a2[s4*4+1]) * h[s4*4+1] + dtx * Bq.y;
                p += h[s4*4+1] * Cq.y;
                h[s4*4+2] = __builtin_amdgcn_exp2f(dtv * a2[s4*4+2]) * h[s4*4+2] + dtx * Bq.z;
                p += h[s4*4+2] * Cq.z;
                h[s4*4+3] = __builtin_amdgcn_exp2f(dtv * a2[s4*4+3]) * h[s4*4+3] + dtx * Bq.w;
                p += h[s4*4+3] * Cq.w;
            }
            float gvv = b2f(pg[(size_t)t * kDI]);
            py[(size_t)t * kDI] = f2bf((p + ddv * xvv) * gvv);
        }
    }

    if (PASS == 0) {
#pragma unroll
        for (int s = 0; s < 16; s++)
            PL[plb + (size_t)s * kDI] = h[s];
        SDT[(size_t)(bb * kG + g) * kDI + d] = sdt;
    }
}

// boundary fix: h_in[chain][g] = scan of (P,L) over groups; P recomputed
// from sdt (exp2(a2*sdt), bit-identical to pass0's former P store).
__global__ __launch_bounds__(256) void bfix_k(float* __restrict__ PL,
    const float* __restrict__ SDT,
    const float* __restrict__ alogf, const float* __restrict__ alogb)
{
    const int idx = blockIdx.x * 256 + threadIdx.x;  // 16 s x 8 bb x 1024 d
    const int d  = idx & (kDI - 1);
    const int bb = (idx >> 10) & 7;
    const int s  = idx >> 13;
    const int dir = bb >> 2;
    const float* alog = dir ? alogb : alogf;
    const float a2 = -__expf(alog[d * kDS + s]) * 1.44269504f;
    float h = 0.f;
    for (int g = 0; g < kG; g++) {
        size_t base = (size_t)(bb * kG + g) * 16 * kDI + d;
        float L = PL[base + (size_t)s * kDI];
        float P = __builtin_amdgcn_exp2f(a2 * SDT[(size_t)(bb * kG + g) * kDI + d]);
        PL[base + (size_t)s * kDI] = h;  // h_in for pass C
        h = P * h + L;
    }
}

// ---------------------------------------------------------------- attention -
__global__ __launch_bounds__(64) void att_score_k(const unsigned short* __restrict__ tmp,
    const float* __restrict__ aw2, const float* __restrict__ ab2,
    float* __restrict__ score)
{
    int row = blockIdx.x, lane = threadIdx.x;
    float acc = 0.f;
#pragma unroll
    for (int j = 0; j < 4; j++)
        acc += b2f(tmp[(size_t)row * 256 + lane + j * 64]) * aw2[lane + j * 64];
    for (int o = 32; o > 0; o >>= 1) acc += __shfl_xor(acc, o, 64);
    if (lane == 0) score[row] = acc + ab2[0];
}

// softmax over each bb row; also zeroes zcat (replaces the memset dispatch --
// pool_k launches after, stream order guarantees visibility).
__global__ __launch_bounds__(256) void softmax_k(const float* __restrict__ score,
                                                 float* __restrict__ w,
                                                 float* __restrict__ zcat)
{
    int bb = blockIdx.x, tid = threadIdx.x;
    if (bb == 0) {
#pragma unroll
        for (int i = 0; i < 4 * kB * 2 * kDM / 1024; i++)   // 4096 floats
            zcat[tid + i * 256] = 0.f;
    }
    float v[4]; float m = -1e30f;
#pragma unroll
    for (int i = 0; i < 4; i++) { v[i] = score[bb * kN + tid + i * 256]; m = fmaxf(m, v[i]); }
    for (int o = 32; o > 0; o >>= 1) m = fmaxf(m, __shfl_xor(m, o, 64));
    __shared__ float r1[4], r2[4];
    int wv = tid >> 6;
    if ((tid & 63) == 0) r1[wv] = m;
    __syncthreads();
    m = fmaxf(fmaxf(r1[0], r1[1]), fmaxf(r1[2], r1[3]));
    float s = 0.f;
#pragma unroll
    for (int i = 0; i < 4; i++) { v[i] = __expf(v[i] - m); s += v[i]; }
    for (int o = 32; o > 0; o >>= 1) s += __shfl_xor(s, o, 64);
    if ((tid & 63) == 0) r2[wv] = s;
    __syncthreads();
    s = r2[0] + r2[1] + r2[2] + r2[3];
    float inv = 1.f / s;
#pragma unroll
    for (int i = 0; i < 4; i++) w[bb * kN + tid + i * 256] = v[i] * inv;
}

__global__ __launch_bounds__(512) void pool_k(const float* __restrict__ w,
    const float* __restrict__ h, float* zcat)
{
    int bb = blockIdx.x, chunk = blockIdx.y;   // 8 x 32
    int d = threadIdx.x;
    float acc = 0.f;
    int n0 = chunk * 32;
    for (int n = n0; n < n0 + 32; n++)
        acc += w[bb * kN + n] * h[((size_t)bb * kN + n) * kDM + d];
    int b = bb & 3, dir = bb >> 2;
    atomicAdd(&zcat[b * (2 * kDM) + dir * kDM + d], acc);
}

__global__ __launch_bounds__(256) void att_out_k(const float* __restrict__ w,
                                                 float* __restrict__ out)
{
    int idx = blockIdx.x * 256 + threadIdx.x;  // kB*kN
    int b = idx >> 10, n = idx & 1023;
    out[idx] = 0.5f * (w[b * kN + n] + w[(b + 4) * kN + (kN - 1 - n)]);
}

// ---------------------------------------------------------------- launch ----
extern "C" void kernel_launch(void* const* d_in, const int* in_sizes, int n_in,
                              void* d_out, int out_size, void* d_ws, size_t ws_size,
                              hipStream_t stream)
{
    const float* x = (const float*)d_in[0];
    const float* fp[17]; const float* bp[17];
    for (int i = 0; i < 17; i++) { fp[i] = (const float*)d_in[1 + i]; bp[i] = (const float*)d_in[18 + i]; }
    const float* aw1 = (const float*)d_in[35];
    const float* ab1 = (const float*)d_in[36];
    const float* aw2 = (const float*)d_in[37];
    const float* ab2 = (const float*)d_in[38];
    const float* nw  = (const float*)d_in[39];
    const float* nb  = (const float*)d_in[40];
    float* out = (float*)d_out;

    float* h = (float*)d_ws;                                   // 8192*512 f32
    unsigned short* ub    = (unsigned short*)(h + (size_t)kROWS * kDM);  // 8192*512
    unsigned short* xbuf  = ub    + (size_t)kROWS * kDM;        // 8192*1024 (x-half / y / ffn1 lo)
    unsigned short* tbuf  = xbuf  + (size_t)kROWS * kDI;        // 8192*1024 (dt / ffn1 hi / hb)
    unsigned short* xhb   = tbuf  + (size_t)kROWS * kDI;        // 8192*1024 (xh row-major)
    unsigned short* gateb = xhb   + (size_t)kROWS * kDI;        // 8192*1024 (gate row-major)
    unsigned short* dbl   = gateb + (size_t)kROWS * kDI;        // 8192*64 bf16
    float* dblF  = (float*)(dbl + (size_t)kROWS * 64);          // 8192*32 f32 (B/C)
    float* score = dblF + (size_t)kROWS * 32;                   // 8192
    float* smw   = score + kROWS;                               // 8192
    float* zcat  = smw   + kROWS;                               // 4096
    unsigned short* wts  = (unsigned short*)(zcat + kB * 2 * kDM);
    float* PL  = (float*)(wts + O_WTOT);                        // 8*32*16*1024 f32 = 16.8MB
    float* SDT = PL + (size_t)kB2 * kG * 16 * kDI;              // 8*32*1024 f32 = 1MB

    // ---- weight prep: fp32 [L][K][N] -> bf16 [L][N][K] (one launch) ----
    WJobs jobs;
    jobs.s[0] = fp[2];  jobs.s[1] = bp[2];
    jobs.s[2] = fp[5];  jobs.s[3] = bp[5];
    jobs.s[4] = fp[6];  jobs.s[5] = bp[6];
    jobs.s[6] = fp[10]; jobs.s[7] = bp[10];
    jobs.s[8] = fp[13]; jobs.s[9] = bp[13];
    jobs.s[10] = fp[15]; jobs.s[11] = bp[15];
    jobs.s[12] = aw1;
    int wblocks = 0;
    {
        const int wK[13] = {512,512,1024,1024,32,32,1024,1024,512,512,2048,2048,512};
        const int wN[13] = {2048,2048,64,64,1024,1024,512,512,2048,2048,512,512,256};
        const int wL[13] = {2,2,2,2,2,2,2,2,2,2,2,2,1};
        for (int j = 0; j < 13; j++) wblocks += wL[j] * (wK[j]/32) * (wN[j]/32);
    }
    wprep_k<<<wblocks, 256, 0, stream>>>(jobs, wts);

    init_h_k<<<kROWS * kDM / 256, 256, 0, stream>>>(x, h);

    for (int l = 0; l < kL; l++) {
        const float *f_n1w = fp[0]  + l * kDM,            *b_n1w = bp[0]  + l * kDM;
        const float *f_n1b = fp[1]  + l * kDM,            *b_n1b = bp[1]  + l * kDM;
        const float *f_cw  = fp[3]  + l * kDI * kDC,      *b_cw  = bp[3]  + l * kDI * kDC;
        const float *f_cb  = fp[4]  + l * kDI,            *b_cb  = bp[4]  + l * kDI;
        const float *f_dtb = fp[7]  + l * kDI,            *b_dtb = bp[7]  + l * kDI;
        const float *f_alog= fp[8]  + l * kDI * kDS,      *b_alog= bp[8]  + l * kDI * kDS;
        const float *f_dd  = fp[9]  + l * kDI,            *b_dd  = bp[9]  + l * kDI;
        const float *f_n2w = fp[11] + l * kDM,            *b_n2w = bp[11] + l * kDM;
        const float *f_n2b = fp[12] + l * kDM,            *b_n2b = bp[12] + l * kDM;
        const float *f_b1  = fp[14] + l * 4 * kDM,        *b_b1  = bp[14] + l * 4 * kDM;
        const float *f_b2  = fp[16] + l * kDM,            *b_b2  = bp[16] + l * kDM;

        const unsigned short *wInwF = wts + O_INW_F + (size_t)l * 2048 * 512;
        const unsigned short *wInwB = wts + O_INW_B + (size_t)l * 2048 * 512;
        const unsigned short *wXpwF = wts + O_XPW_F + (size_t)l * 64 * 1024;
        const unsigned short *wXpwB = wts + O_XPW_B + (size_t)l * 64 * 1024;
        const unsigned short *wDtwF = wts + O_DTW_F + (size_t)l * 1024 * 32;
        const unsigned short *wDtwB = wts + O_DTW_B + (size_t)l * 1024 * 32;
        const unsigned short *wOwF  = wts + O_OW_F  + (size_t)l * 512 * 1024;
        const unsigned short *wOwB  = wts + O_OW_B  + (size_t)l * 512 * 1024;
        const unsigned short *wW1F  = wts + O_W1_F  + (size_t)l * 2048 * 512;
        const unsigned short *wW1B  = wts + O_W1_B  + (size_t)l * 2048 * 512;
        const unsigned short *wW2F  = wts + O_W2_F  + (size_t)l * 512 * 2048;
        const unsigned short *wW2B  = wts + O_W2_B  + (size_t)l * 512 * 2048;

        // u = LN1(h) -> bf16
        ln_k<kDM,1><<<kROWS, 256, 0, stream>>>(h, f_n1w, b_n1w, f_n1b, b_n1b, ub);
        // x-half -> xbuf bf16 [row][kDI]; z-half -> gateb = silu(z) row-major
        gemm_mfma<128,128,EPI_NONE,0,MODE_GATE,1,64,512,4><<<dim3(16, 64), 512, 0, stream>>>(
            ub, kDM, kDM, wInwF, wInwB, nullptr, nullptr, xbuf, kDI, gateb);
        // xh[row][kDI] = silu(conv(xbuf) + cb)  (2-wide vectorized)
        conv_k<<<dim3(kN/64, kDI/64, kB2), 256, 0, stream>>>(
            xbuf, f_cw, b_cw, f_cb, b_cb, xhb);
        // dbl = xh @ xpw (A row-major); cols>=32 also -> dblF f32 [row][32]
        gemm_mfma<32,64,EPI_NONE,0,MODE_DBL,1,64><<<dim3(1, 256), 256, 0, stream>>>(
            xhb, kDI, kDI, wXpwF, wXpwB, nullptr, nullptr, dbl, 64, (unsigned short*)dblF);
        // dt[row][kDI] = softplus(dbl[:, :32] @ dtw + dtb)  (row-major)
        gemm_mfma<128,128,EPI_SOFTPLUS,0,MODE_N,1,32><<<dim3(8, 64), 256, 0, stream>>>(
            dbl, 64, kDTR, wDtwF, wDtwB, f_dtb, b_dtb, tbuf, kDI, nullptr);
        // blocked scan: local pass -> boundary fix -> full pass (y into xbuf)
        bscan_k<0><<<dim3(kDI/256, kG, kB2), 256, 0, stream>>>(
            tbuf, xhb, gateb, dblF, xbuf, PL, SDT, f_alog, b_alog, f_dd, b_dd);
        bfix_k<<<kB2 * kDI * kDS / 256, 256, 0, stream>>>(PL, SDT, f_alog, b_alog);
        bscan_k<1><<<dim3(kDI/256, kG, kB2), 256, 0, stream>>>(
            tbuf, xhb, gateb, dblF, xbuf, PL, SDT, f_alog, b_alog, f_dd, b_dd);
        // h += y @ ow  (512-thread / 8-wave blocks, 4M x 2N)
        gemm_mfma<128,64,EPI_RESID,0,MODE_N,0,64,512,2><<<dim3(8, 64), 512, 0, stream>>>(
            xbuf, kDI, kDI, wOwF, wOwB, nullptr, nullptr, h, kDM, nullptr);
        // u = LN2(h) -> bf16
        ln_k<kDM,1><<<kROWS, 256, 0, stream>>>(h, f_n2w, b_n2w, f_n2b, b_n2b, ub);
        // ffn1: gelu(u @ w1 + b1) -> xbuf..tbuf slab bf16 (8192 x 2048)
        gemm_mfma<128,128,EPI_GELU,0,MODE_N,1,64,512,4><<<dim3(16, 64), 512, 0, stream>>>(
            ub, kDM, kDM, wW1F, wW1B, f_b1, b_b1, xbuf, 4*kDM, nullptr);
        // h += ffn1 @ w2 + b2; last layer also emits bf16 h into tbuf
        if (l == kL - 1) {
            gemm_mfma<128,64,EPI_RESID_BIAS,0,MODE_RESB16,0,64,512,2><<<dim3(8, 64), 512, 0, stream>>>(
                xbuf, 4*kDM, 4*kDM, wW2F, wW2B, f_b2, b_b2, h, kDM, tbuf);
        } else {
            gemm_mfma<128,64,EPI_RESID_BIAS,0,MODE_N,0,64,512,2><<<dim3(8, 64), 512, 0, stream>>>(
                xbuf, 4*kDM, 4*kDM, wW2F, wW2B, f_b2, b_b2, h, kDM, nullptr);
        }
    }

    // attention: u = tanh(hb @ aw1 + ab1) bf16 (hb = tbuf, emitted by w2)
    gemm_mfma<64,128,EPI_TANH,0,MODE_N,1,64><<<dim3(2, 128), 256, 0, stream>>>(
        tbuf, kDM, kDM, wts + O_AW1, wts + O_AW1, ab1, ab1, ub, 256, nullptr);
    att_score_k<<<kROWS, 64, 0, stream>>>(ub, aw2, ab2, score);
    softmax_k<<<kB2, 256, 0, stream>>>(score, smw, zcat);   // also zeroes zcat
    pool_k<<<dim3(kB2, 32), 512, 0, stream>>>(smw, h, zcat);
    // out[0:4096] = LN(concat(zf, zb))
    ln_k<2*kDM,0><<<kB, 256, 0, stream>>>(zcat, nw, nw, nb, nb, out);
    // out[4096:8192] = 0.5*(af + flip(ab))
    att_out_k<<<kB * kN / 256, 256, 0, stream>>>(smw, out + kB * 2 * kDM);
}

// Round 13
// 637.057 us; speedup vs baseline: 1.0464x; 1.0075x over previous
//
#include <hip/hip_runtime.h>
#include <math.h>

constexpr int kDM   = 512;
constexpr int kDI   = 1024;
constexpr int kDS   = 16;
constexpr int kDC   = 4;
constexpr int kDTR  = 32;
constexpr int kL    = 2;
constexpr int kB    = 4;
constexpr int kN    = 1024;
constexpr int kB2   = 8;              // combined batch: rows 0-3 fwd, 4-7 bwd
constexpr int kROWS = kB2 * kN;       // 8192
constexpr int kMDIR = kB * kN;        // 4096 rows per direction

enum { EPI_NONE=0, EPI_SOFTPLUS=1, EPI_RESID=2, EPI_GELU=3, EPI_RESID_BIAS=4, EPI_TANH=5 };
enum { MODE_N=0, MODE_OTR=1, MODE_DBL=2, MODE_GATE=3, MODE_RESB16=4 };

typedef __attribute__((ext_vector_type(8))) short bf16x8;
typedef __attribute__((ext_vector_type(4))) short bf16x4;
typedef __attribute__((ext_vector_type(4))) float f32x4;

__device__ __forceinline__ unsigned short f2bf(float f) {
    unsigned int u = __float_as_uint(f);
    return (unsigned short)((u + 0x7FFFu + ((u >> 16) & 1u)) >> 16);
}
__device__ __forceinline__ float b2f(unsigned short u) {
    return __uint_as_float((unsigned int)u << 16);
}

// Abramowitz-Stegun 7.1.26 erf: max err 1.5e-7 (+ ~1e-7 from v_rcp) --
// far below bf16 LSB (2^-8 rel), replaces branchy libm erff (~50 inst -> ~14).
__device__ __forceinline__ float erf_as(float x) {
    float ax = fabsf(x);
    float t  = __builtin_amdgcn_rcpf(1.f + 0.3275911f * ax);
    float p  = t * (0.254829592f + t * (-0.284496736f + t * (1.421413741f +
               t * (-1.453152027f + t * 1.061405429f))));
    float e  = __builtin_amdgcn_exp2f(ax * ax * -1.44269504f);
    float r  = 1.f - p * e;
    return __builtin_copysignf(r, x);
}

// global -> LDS 16-B DMA (one instruction, no VGPR round-trip)
#define GLD_LDS16(gsrc, ldst) \
    __builtin_amdgcn_global_load_lds((const __attribute__((address_space(1))) void*)(gsrc), \
                                     (__attribute__((address_space(3))) void*)(ldst), 16, 0, 0)

// ------------------------------------------------------- weight prep --------
struct WJobs { const float* s[13]; };
// job order: f_inw b_inw f_xpw b_xpw f_dtw b_dtw f_ow b_ow f_w1 b_w1 f_w2 b_w2 aw1
constexpr size_t O_INW_F = 0;
constexpr size_t O_INW_B = O_INW_F + 2u*512*2048;
constexpr size_t O_XPW_F = O_INW_B + 2u*512*2048;
constexpr size_t O_XPW_B = O_XPW_F + 2u*1024*64;
constexpr size_t O_DTW_F = O_XPW_B + 2u*1024*64;
constexpr size_t O_DTW_B = O_DTW_F + 2u*32*1024;
constexpr size_t O_OW_F  = O_DTW_B + 2u*32*1024;
constexpr size_t O_OW_B  = O_OW_F  + 2u*1024*512;
constexpr size_t O_W1_F  = O_OW_B  + 2u*1024*512;
constexpr size_t O_W1_B  = O_W1_F  + 2u*512*2048;
constexpr size_t O_W2_F  = O_W1_B  + 2u*512*2048;
constexpr size_t O_W2_B  = O_W2_F  + 2u*2048*512;
constexpr size_t O_AW1   = O_W2_B  + 2u*2048*512;
constexpr size_t O_WTOT  = O_AW1   + 1u*512*256;

__global__ __launch_bounds__(256) void wprep_k(WJobs jobs, unsigned short* __restrict__ dst)
{
    const int wK[13] = {512,512,1024,1024,32,32,1024,1024,512,512,2048,2048,512};
    const int wN[13] = {2048,2048,64,64,1024,1024,512,512,2048,2048,512,512,256};
    const int wL[13] = {2,2,2,2,2,2,2,2,2,2,2,2,1};
    int blk = blockIdx.x;
    int j = 0; int base = 0; size_t doff = 0;
    for (; j < 13; j++) {
        int nb = wL[j] * (wK[j] / 32) * (wN[j] / 32);
        if (blk < base + nb) break;
        base += nb;
        doff += (size_t)wL[j] * wK[j] * wN[j];
    }
    int rel = blk - base;
    int K = wK[j], N = wN[j];
    int tk = K / 32, tn = N / 32;
    int l = rel / (tk * tn); rel -= l * tk * tn;
    int kt = rel / tn, nt = rel - (rel / tn) * tn;
    const float* src = jobs.s[j] + (size_t)l * K * N;
    unsigned short* d = dst + doff + (size_t)l * K * N;
    __shared__ float tl[32][33];
    const int c = threadIdx.x & 31, rg = threadIdx.x >> 5;
#pragma unroll
    for (int rr = 0; rr < 4; rr++)
        tl[rg * 4 + rr][c] = src[(size_t)(kt * 32 + rg * 4 + rr) * N + nt * 32 + c];
    __syncthreads();
#pragma unroll
    for (int rr = 0; rr < 4; rr++)
        d[(size_t)(nt * 32 + rg * 4 + rr) * K + kt * 32 + c] = f2bf(tl[c][rg * 4 + rr]);
}

// ---------------------------------------------------------------- init h ----
__global__ __launch_bounds__(256) void init_h_k(const float* __restrict__ x,
                                                float* __restrict__ h)
{
    size_t idx = (size_t)blockIdx.x * 256 + threadIdx.x;   // kROWS*kDM
    int d  = idx & (kDM - 1);
    int t  = (idx >> 9) & (kN - 1);
    int bb = (int)(idx >> 19);
    int b = bb & 3, dir = bb >> 2;
    int ts = dir ? (kN - 1 - t) : t;
    h[idx] = x[((size_t)b * kN + ts) * kDM + d];
}

// ---------------------------------------------------------------- layernorm --
template<int DIM, int OBF>
__global__ __launch_bounds__(256) void ln_k(const float* __restrict__ x,
    const float* __restrict__ wf, const float* __restrict__ wb,
    const float* __restrict__ bf, const float* __restrict__ bbp,
    void* __restrict__ outv)
{
    const int row = blockIdx.x;
    const int tid = threadIdx.x;
    constexpr int PT = DIM / 256;
    const int dir = (row >= kMDIR) ? 1 : 0;
    const float* w = dir ? wb : wf;
    const float* b = dir ? bbp : bf;

    float v[PT];
    float s1 = 0.f, s2 = 0.f;
#pragma unroll
    for (int i = 0; i < PT; i++) {
        float t = x[(size_t)row * DIM + tid + i * 256];
        v[i] = t; s1 += t; s2 += t * t;
    }
    for (int o = 32; o > 0; o >>= 1) { s1 += __shfl_xor(s1, o, 64); s2 += __shfl_xor(s2, o, 64); }
    __shared__ float r1[4], r2[4];
    int wv = tid >> 6;
    if ((tid & 63) == 0) { r1[wv] = s1; r2[wv] = s2; }
    __syncthreads();
    s1 = r1[0] + r1[1] + r1[2] + r1[3];
    s2 = r2[0] + r2[1] + r2[2] + r2[3];
    float mu  = s1 / DIM;
    float var = s2 / DIM - mu * mu;
    float rr  = rsqrtf(var + 1e-5f);
#pragma unroll
    for (int i = 0; i < PT; i++) {
        int c = tid + i * 256;
        float o = (v[i] - mu) * rr * w[c] + b[c];
        if (OBF) ((unsigned short*)outv)[(size_t)row * DIM + c] = f2bf(o);
        else     ((float*)outv)[(size_t)row * DIM + c] = o;
    }
}

// ---------------------------------------------------------------- MFMA GEMM -
// C = A @ B (+bias)(+epilogue). A bf16 [M][lda], B^T bf16 [N][K].
// KB==64: r18/r9 2-phase double-buffer DMA K-loop (proven; r19's
// counted-vmcnt graft regressed). r22: NTH/WSN applied to the small GEMMs
// too -- xpw was 256 blocks = 1 wave/SIMD with 16 latency-exposed K-iters
// (same starvation R8 fixed for the big GEMMs); dtw/aw1 bumped to 512 thr.
template<int BM, int BN, int EPI, int ATR, int MODE, int OBF, int KB,
         int NTH = 256, int WSN = 2>
__global__ __launch_bounds__(NTH) void gemm_mfma(
    const unsigned short* __restrict__ A, int lda, int K,
    const unsigned short* __restrict__ Btf, const unsigned short* __restrict__ Btb,
    const float* __restrict__ biasf, const float* __restrict__ biasb,
    void* __restrict__ Cv, int ldc, unsigned short* __restrict__ Ct)
{
    constexpr int SK  = 40;              // padded LDS row stride (old path)
    constexpr int KT  = KB / 32;         // 32-wide sub-tiles per stage
    constexpr int CPR = KB / 8;          // 8-elem chunks per row (old path)
    constexpr int WAVES = NTH / 64;
    constexpr int WSM = WAVES / WSN;
    constexpr int WM  = BM / WSM, WN = BN / WSN;
    constexpr int MT  = WM / 16, NT = WN / 16;
    constexpr int ASL = (BM * KB) / (NTH * 8);
    constexpr int BSL = (BN * KB) / (NTH * 8);
    constexpr int ABUF = BM * 64;        // one K-tile of A (ushorts)
    constexpr int BBUF = BN * 64;
    constexpr int ASZ = (KB == 64) ? 2 * ABUF : KT * BM * SK;
    constexpr int BSZ = (KB == 64) ? 2 * BBUF : KT * BN * SK;

    __shared__ __align__(16) unsigned short As[ASZ];
    __shared__ __align__(16) unsigned short Bs[BSZ];

    const int tid  = threadIdx.x;
    // ---- XCD swizzle (T1, bijective: nwg % 8 == 0 for every launch here) --
    const int gx   = gridDim.x;
    const int nwg  = gx * gridDim.y;
    const int lin  = blockIdx.x + blockIdx.y * gx;
    const int swz  = (lin & 7) * (nwg >> 3) + (lin >> 3);
    const int by   = swz / gx;
    const int bx   = swz - by * gx;
    const int n0   = bx * BN;
    const int row0 = by * BM;
    const int dir  = (row0 >= kMDIR) ? 1 : 0;
    const unsigned short* __restrict__ Bt = dir ? Btb : Btf;
    const float* bias = dir ? biasb : biasf;

    const int lane = tid & 63;
    const int wave = tid >> 6;
    const int wr = wave / WSN, wc = wave % WSN;
    const int ml = lane & 15, q = lane >> 4;

    f32x4 acc[MT][NT];
#pragma unroll
    for (int i = 0; i < MT; i++)
#pragma unroll
        for (int j = 0; j < NT; j++)
#pragma unroll
            for (int r = 0; r < 4; r++) acc[i][j][r] = 0.f;

    if constexpr (KB == 64) {
        // ---- 2-phase double-buffered DMA K-loop (r18 structure) ----
        constexpr int ACW = (BM / 8) / WAVES;   // 1-KB chunks per wave (A)
        constexpr int BCW = (BN / 8) / WAVES;   // 1-KB chunks per wave (B)
        const int lrow = lane >> 3;                       // 0..7 row in chunk
        const int lcol = ((lane & 7) ^ (lrow & 7)) << 4;  // pre-swizzled col byte
        const char* aS[ACW ? ACW : 1];
        const char* bS[BCW ? BCW : 1];
#pragma unroll
        for (int ch = 0; ch < ACW; ch++) {
            const int chunk = wave * ACW + ch;
            aS[ch] = (const char*)A + (size_t)(row0 + chunk * 8 + lrow) * lda * 2 + lcol;
        }
#pragma unroll
        for (int ch = 0; ch < BCW; ch++) {
            const int chunk = wave * BCW + ch;
            bS[ch] = (const char*)Bt + (size_t)(n0 + chunk * 8 + lrow) * K * 2 + lcol;
        }
        const int axor = (ml & 7) << 3;  // read-side swizzle (ushort units)

        auto stage = [&](int buf) {
#pragma unroll
            for (int ch = 0; ch < ACW; ch++) {
                GLD_LDS16(aS[ch], &As[buf * ABUF + (wave * ACW + ch) * 512]);
                aS[ch] += 128;
            }
#pragma unroll
            for (int ch = 0; ch < BCW; ch++) {
                GLD_LDS16(bS[ch], &Bs[buf * BBUF + (wave * BCW + ch) * 512]);
                bS[ch] += 128;
            }
        };

        stage(0);
        __syncthreads();                 // buf0 staged (vmcnt(0) + barrier)
        const int NKT = K >> 6;
        int cur = 0;
        for (int t = 0; t < NKT; t++) {
            if (t + 1 < NKT) stage(cur ^ 1);   // prefetch BEFORE compute
#pragma unroll
            for (int kk = 0; kk < 2; kk++) {
                bf16x8 af[MT], bfr[NT];
#pragma unroll
                for (int i = 0; i < MT; i++)
                    af[i] = *(bf16x8*)&As[cur * ABUF + (wr * WM + i * 16 + ml) * 64 + ((kk * 32 + q * 8) ^ axor)];
#pragma unroll
                for (int j = 0; j < NT; j++)
                    bfr[j] = *(bf16x8*)&Bs[cur * BBUF + (wc * WN + j * 16 + ml) * 64 + ((kk * 32 + q * 8) ^ axor)];
#pragma unroll
                for (int i = 0; i < MT; i++)
#pragma unroll
                    for (int j = 0; j < NT; j++)
                        acc[i][j] = __builtin_amdgcn_mfma_f32_16x16x32_bf16(af[i], bfr[j], acc[i][j], 0, 0, 0);
            }
            __syncthreads();   // per-wave vmcnt(0): next buf staged; lgkm(0): cur reads done
            cur ^= 1;
        }
    } else {
        // ---- old reg-staging path (KB==32: dtw GEMM only) ----
        for (int kt = 0; kt < K; kt += KB) {
            bf16x8 a_ld[ASL ? ASL : 1];
#pragma unroll
            for (int r = 0; r < ASL; r++) {
                int i = tid + r * NTH;
                int m = i / CPR, c8 = (i % CPR) * 8;
                a_ld[r] = *(const bf16x8*)(A + (size_t)(row0 + m) * lda + kt + c8);
            }
            bf16x8 b_ld[BSL ? BSL : 1];
#pragma unroll
            for (int r = 0; r < BSL; r++) {
                int i = tid + r * NTH;
                int n = i / CPR, c8 = (i % CPR) * 8;
                b_ld[r] = *(const bf16x8*)(Bt + (size_t)(n0 + n) * K + kt + c8);
            }
            __syncthreads();
#pragma unroll
            for (int r = 0; r < ASL; r++) {
                int i = tid + r * NTH;
                int m = i / CPR, c8 = (i % CPR) * 8;
                *(bf16x8*)&As[((c8 >> 5) * BM + m) * SK + (c8 & 31)] = a_ld[r];
            }
#pragma unroll
            for (int r = 0; r < BSL; r++) {
                int i = tid + r * NTH;
                int n = i / CPR, c8 = (i % CPR) * 8;
                *(bf16x8*)&Bs[((c8 >> 5) * BN + n) * SK + (c8 & 31)] = b_ld[r];
            }
            __syncthreads();
#pragma unroll
            for (int kk = 0; kk < KT; kk++) {
                bf16x8 af[MT], bfr[NT];
#pragma unroll
                for (int i = 0; i < MT; i++)
                    af[i] = *(bf16x8*)&As[(kk * BM + wr * WM + i * 16 + ml) * SK + q * 8];
#pragma unroll
                for (int j = 0; j < NT; j++)
                    bfr[j] = *(bf16x8*)&Bs[(kk * BN + wc * WN + j * 16 + ml) * SK + q * 8];
#pragma unroll
                for (int i = 0; i < MT; i++)
#pragma unroll
                    for (int j = 0; j < NT; j++)
                        acc[i][j] = __builtin_amdgcn_mfma_f32_16x16x32_bf16(af[i], bfr[j], acc[i][j], 0, 0, 0);
            }
            __syncthreads();
        }
    }

    // ---- epilogue ----
    float* Cf = (float*)Cv;
    unsigned short* Cb = (unsigned short*)Cv;
#pragma unroll
    for (int j = 0; j < NT; j++) {
        int col = n0 + wc * WN + j * 16 + ml;
        float bv = 0.f;
        if (EPI == EPI_SOFTPLUS || EPI == EPI_GELU || EPI == EPI_RESID_BIAS || EPI == EPI_TANH)
            bv = bias[col];
#pragma unroll
        for (int i = 0; i < MT; i++) {
            int rw = row0 + wr * WM + i * 16 + q * 4;
            float v4[4];
#pragma unroll
            for (int r = 0; r < 4; r++) {
                float v = acc[i][j][r] + bv;
                if (EPI == EPI_SOFTPLUS) v = (v > 20.f) ? v : __logf(1.f + __expf(v));
                if (EPI == EPI_GELU)     v = 0.5f * v * (1.f + erf_as(v * 0.70710678118654752f));
                if (EPI == EPI_TANH)     v = tanhf(v);
                v4[r] = v;
            }
            if (MODE == MODE_GATE && n0 >= kDI) {
                // silu(z) -> gate row-major [row][kDI]
#pragma unroll
                for (int r = 0; r < 4; r++) {
                    float sv = v4[r] / (1.f + __expf(-v4[r]));
                    Ct[(size_t)(rw + r) * kDI + (col - kDI)] = f2bf(sv);
                }
            } else {
#pragma unroll
                for (int r = 0; r < 4; r++) {
                    size_t o = (size_t)(rw + r) * ldc + col;
                    if (EPI == EPI_RESID || EPI == EPI_RESID_BIAS) {
                        float nv = Cf[o] + v4[r];
                        Cf[o] = nv;
                        if (MODE == MODE_RESB16) Ct[o] = f2bf(nv);   // fused h->bf16
                    }
                    else if (OBF) Cb[o] = f2bf(v4[r]);
                    else Cf[o] = v4[r];
                }
                if (MODE == MODE_DBL && col >= 32) {
                    float* F = (float*)Ct;          // dblF f32 [row][32]
#pragma unroll
                    for (int r = 0; r < 4; r++)
                        F[(size_t)(rw + r) * 32 + (col - 32)] = v4[r];
                }
            }
        }
    }
}

// ---------------------------------------------------------------- conv ------
// xb bf16 [row][kDI] (x-half) -> xh bf16 [row][kDI] = silu(causal conv + cb).
// 2-wide vectorized (uint = 2 bf16 per load/store; 64-d blocks).
__global__ __launch_bounds__(256) void conv_k(const unsigned short* __restrict__ xb,
    const float* __restrict__ cwf, const float* __restrict__ cwb,
    const float* __restrict__ cbf, const float* __restrict__ cbb,
    unsigned short* __restrict__ xh)
{
    __shared__ float tl[67][66];
    const int t0 = blockIdx.x * 64, d0 = blockIdx.y * 64, bb = blockIdx.z;
    const int dir = bb >> 2;
    const float* cw = dir ? cwb : cwf;
    const float* cb = dir ? cbb : cbf;
    const int dl = (threadIdx.x & 31) * 2, rl = threadIdx.x >> 5;
    const size_t base = (size_t)bb * kN * kDI + d0 + dl;
#pragma unroll
    for (int p = 0; p < 9; p++) {
        int r = p * 8 + rl;
        if (r < 67) {
            int ts = t0 + r - 3;
            unsigned int u = (ts >= 0) ? *(const unsigned int*)(xb + base + (size_t)ts * kDI) : 0u;
            tl[r][dl]     = __uint_as_float(u << 16);
            tl[r][dl + 1] = __uint_as_float(u & 0xffff0000u);
        }
    }
    __syncthreads();
    const int g0 = d0 + dl;
    float c00 = cw[g0*4+0], c01 = cw[g0*4+1], c02 = cw[g0*4+2], c03 = cw[g0*4+3];
    float c10 = cw[g0*4+4], c11 = cw[g0*4+5], c12 = cw[g0*4+6], c13 = cw[g0*4+7];
    float bv0 = cb[g0], bv1 = cb[g0 + 1];
#pragma unroll
    for (int jj = 0; jj < 8; jj++) {
        int tt = rl + 8 * jj;
        float a0 = bv0 + c00*tl[tt][dl]   + c01*tl[tt+1][dl]   + c02*tl[tt+2][dl]   + c03*tl[tt+3][dl];
        float a1 = bv1 + c10*tl[tt][dl+1] + c11*tl[tt+1][dl+1] + c12*tl[tt+2][dl+1] + c13*tl[tt+3][dl+1];
        float o0 = a0 / (1.f + __expf(-a0));
        float o1 = a1 / (1.f + __expf(-a1));
        unsigned int w = (unsigned int)f2bf(o0) | ((unsigned int)f2bf(o1) << 16);
        *(unsigned int*)(xh + (size_t)(bb * kN + t0 + tt) * kDI + g0) = w;
    }
}

// ---------------------------------------------------------------- scan ------
// r14 coalesced blocked scan + r20 PL-thinning: pass0 stores only L (16
// slots) + a per-(chain,group) sdt scalar; bfix recomputes P = exp2(a2*sdt).
constexpr int kG  = 32;           // groups per chain
constexpr int kTg = kN / kG;      // 32 timesteps per group

template<int PASS>
__global__ __launch_bounds__(256) void bscan_k(
    const unsigned short* __restrict__ dt,   // [row][kDI]
    const unsigned short* __restrict__ xh,   // [row][kDI]
    const unsigned short* __restrict__ gate, // [row][kDI]
    const float* __restrict__ dblF,          // [row][32] (B | C)
    unsigned short* __restrict__ y,          // [row][kDI]
    float* __restrict__ PL,                  // [bb][g][16 L-slots][kDI]
    float* __restrict__ SDT,                 // [bb][g][kDI]
    const float* __restrict__ alogf, const float* __restrict__ alogb,
    const float* __restrict__ ddf,   const float* __restrict__ ddb)
{
    const int d  = blockIdx.x * 256 + threadIdx.x;   // 0..1023
    const int g  = blockIdx.y;                       // 0..31
    const int bb = blockIdx.z;                       // 0..7
    const int dir = bb >> 2;
    const float* alog = dir ? alogb : alogf;
    const float* ddp  = dir ? ddb  : ddf;

    float a2[16];
#pragma unroll
    for (int s = 0; s < 16; s += 4) {
        float4 al = *(const float4*)&alog[d * kDS + s];
        a2[s+0] = -__expf(al.x) * 1.44269504f;
        a2[s+1] = -__expf(al.y) * 1.44269504f;
        a2[s+2] = -__expf(al.z) * 1.44269504f;
        a2[s+3] = -__expf(al.w) * 1.44269504f;
    }

    const size_t plb = (size_t)(bb * kG + g) * 16 * kDI + d;   // L-slot stride kDI
    float h[16];
    if (PASS == 0) {
#pragma unroll
        for (int s = 0; s < 16; s++) h[s] = 0.f;
    } else {
#pragma unroll
        for (int s = 0; s < 16; s++) h[s] = PL[plb + (size_t)s * kDI];
    }

    const int row0 = bb * kN + g * kTg;
    const unsigned short* pd = dt   + (size_t)row0 * kDI + d;
    const unsigned short* px = xh   + (size_t)row0 * kDI + d;
    const unsigned short* pg = gate + (size_t)row0 * kDI + d;
    const float* pbc = dblF + (size_t)row0 * 32;
    unsigned short* py = y + (size_t)row0 * kDI + d;
    const float ddv = ddp[d];
    float sdt = 0.f;

#pragma unroll 4
    for (int t = 0; t < kTg; t++) {
        float dtv = b2f(pd[(size_t)t * kDI]);
        float xvv = b2f(px[(size_t)t * kDI]);
        float dtx = dtv * xvv;
        const float* bc = pbc + t * 32;
        if (PASS == 0) {
            sdt += dtv;
#pragma unroll
            for (int s4 = 0; s4 < 4; s4++) {
                float4 Bq = *(const float4*)(bc + s4 * 4);
                h[s4*4+0] = __builtin_amdgcn_exp2f(dtv * a2[s4*4+0]) * h[s4*4+0] + dtx * Bq.x;
                h[s4*4+1] = __builtin_amdgcn_exp2f(dtv * a2[s4*4+1]) * h[s4*4+1] + dtx * Bq.y;
                h[s4*4+2] = __builtin_amdgcn_exp2f(dtv * a2[s4*4+2]) * h[s4*4+2] + dtx * Bq.z;
                h[s4*4+3] = __builtin_amdgcn_exp2f(dtv * a2[s4*4+3]) * h[s4*4+3] + dtx * Bq.w;
            }
        } else {
            float p = 0.f;
#pragma unroll
            for (int s4 = 0; s4 < 4; s4++) {
                float4 Bq = *(const float4*)(bc + s4 * 4);
                float4 Cq = *(const float4*)(bc + 16 + s4 * 4);
                h[s4*4+0] = __builtin_amdgcn_exp2f(dtv * a2[s4*4+0]) * h[s4*4+0] + dtx * Bq.x;
                p += h[s4*4+0] * Cq.x;
                h[s4*4+1] = __builtin_amdgcn_exp2f(dtv * a2[s4*4+1]) * h[s4*4+1] + dtx * Bq.y;
                p += h[s4*4+1] * Cq.y;
                h[s4*4+2] = __builtin_amdgcn_exp2f(dtv * a2[s4*4+2]) * h[s4*4+2] + dtx * Bq.z;
                p += h[s4*4+2] * Cq.z;
                h[s4*4+3] = __builtin_amdgcn_exp2f(dtv * a2[s4*4+3]) * h[s4*4+3] + dtx * Bq.w;
                p += h[s4*4+3] * Cq.w;
            }
            float gvv = b2f(pg[(size_t)t * kDI]);
            py[(size_t)t * kDI] = f2bf((p + ddv * xvv) * gvv);
        }
    }

    if (PASS == 0) {
#pragma unroll
        for (int s = 0; s < 16; s++)
            PL[plb + (size_t)s * kDI] = h[s];
        SDT[(size_t)(bb * kG + g) * kDI + d] = sdt;
    }
}

// boundary fix: h_in[chain][g] = scan of (P,L) over groups; P recomputed
// from sdt. r22: unroll 4 -- the P/L loads are independent of the h
// recurrence, so unrolling lets the compiler hoist 4 iterations of loads
// over the dependent fma chain (was fully latency-serialized).
__global__ __launch_bounds__(256) void bfix_k(float* __restrict__ PL,
    const float* __restrict__ SDT,
    const float* __restrict__ alogf, const float* __restrict__ alogb)
{
    const int idx = blockIdx.x * 256 + threadIdx.x;  // 16 s x 8 bb x 1024 d
    const int d  = idx & (kDI - 1);
    const int bb = (idx >> 10) & 7;
    const int s  = idx >> 13;
    const int dir = bb >> 2;
    const float* alog = dir ? alogb : alogf;
    const float a2 = -__expf(alog[d * kDS + s]) * 1.44269504f;
    float h = 0.f;
#pragma unroll 4
    for (int g = 0; g < kG; g++) {
        size_t base = (size_t)(bb * kG + g) * 16 * kDI + d;
        float L = PL[base + (size_t)s * kDI];
        float P = __builtin_amdgcn_exp2f(a2 * SDT[(size_t)(bb * kG + g) * kDI + d]);
        PL[base + (size_t)s * kDI] = h;  // h_in for pass C
        h = P * h + L;
    }
}

// ---------------------------------------------------------------- attention -
// r22: 4 rows per 256-thread block (was 8192 one-wave blocks).
__global__ __launch_bounds__(256) void att_score_k(const unsigned short* __restrict__ tmp,
    const float* __restrict__ aw2, const float* __restrict__ ab2,
    float* __restrict__ score)
{
    int row = blockIdx.x * 4 + (threadIdx.x >> 6);
    int lane = threadIdx.x & 63;
    float acc = 0.f;
#pragma unroll
    for (int j = 0; j < 4; j++)
        acc += b2f(tmp[(size_t)row * 256 + lane + j * 64]) * aw2[lane + j * 64];
    for (int o = 32; o > 0; o >>= 1) acc += __shfl_xor(acc, o, 64);
    if (lane == 0) score[row] = acc + ab2[0];
}

// softmax over each bb row; also zeroes zcat (replaces the memset dispatch --
// pool_k launches after, stream order guarantees visibility).
__global__ __launch_bounds__(256) void softmax_k(const float* __restrict__ score,
                                                 float* __restrict__ w,
                                                 float* __restrict__ zcat)
{
    int bb = blockIdx.x, tid = threadIdx.x;
    if (bb == 0) {
#pragma unroll
        for (int i = 0; i < 4 * kB * 2 * kDM / 1024; i++)   // 4096 floats
            zcat[tid + i * 256] = 0.f;
    }
    float v[4]; float m = -1e30f;
#pragma unroll
    for (int i = 0; i < 4; i++) { v[i] = score[bb * kN + tid + i * 256]; m = fmaxf(m, v[i]); }
    for (int o = 32; o > 0; o >>= 1) m = fmaxf(m, __shfl_xor(m, o, 64));
    __shared__ float r1[4], r2[4];
    int wv = tid >> 6;
    if ((tid & 63) == 0) r1[wv] = m;
    __syncthreads();
    m = fmaxf(fmaxf(r1[0], r1[1]), fmaxf(r1[2], r1[3]));
    float s = 0.f;
#pragma unroll
    for (int i = 0; i < 4; i++) { v[i] = __expf(v[i] - m); s += v[i]; }
    for (int o = 32; o > 0; o >>= 1) s += __shfl_xor(s, o, 64);
    if ((tid & 63) == 0) r2[wv] = s;
    __syncthreads();
    s = r2[0] + r2[1] + r2[2] + r2[3];
    float inv = 1.f / s;
#pragma unroll
    for (int i = 0; i < 4; i++) w[bb * kN + tid + i * 256] = v[i] * inv;
}

__global__ __launch_bounds__(512) void pool_k(const float* __restrict__ w,
    const float* __restrict__ h, float* zcat)
{
    int bb = blockIdx.x, chunk = blockIdx.y;   // 8 x 32
    int d = threadIdx.x;
    float acc = 0.f;
    int n0 = chunk * 32;
    for (int n = n0; n < n0 + 32; n++)
        acc += w[bb * kN + n] * h[((size_t)bb * kN + n) * kDM + d];
    int b = bb & 3, dir = bb >> 2;
    atomicAdd(&zcat[b * (2 * kDM) + dir * kDM + d], acc);
}

__global__ __launch_bounds__(256) void att_out_k(const float* __restrict__ w,
                                                 float* __restrict__ out)
{
    int idx = blockIdx.x * 256 + threadIdx.x;  // kB*kN
    int b = idx >> 10, n = idx & 1023;
    out[idx] = 0.5f * (w[b * kN + n] + w[(b + 4) * kN + (kN - 1 - n)]);
}

// ---------------------------------------------------------------- launch ----
extern "C" void kernel_launch(void* const* d_in, const int* in_sizes, int n_in,
                              void* d_out, int out_size, void* d_ws, size_t ws_size,
                              hipStream_t stream)
{
    const float* x = (const float*)d_in[0];
    const float* fp[17]; const float* bp[17];
    for (int i = 0; i < 17; i++) { fp[i] = (const float*)d_in[1 + i]; bp[i] = (const float*)d_in[18 + i]; }
    const float* aw1 = (const float*)d_in[35];
    const float* ab1 = (const float*)d_in[36];
    const float* aw2 = (const float*)d_in[37];
    const float* ab2 = (const float*)d_in[38];
    const float* nw  = (const float*)d_in[39];
    const float* nb  = (const float*)d_in[40];
    float* out = (float*)d_out;

    float* h = (float*)d_ws;                                   // 8192*512 f32
    unsigned short* ub    = (unsigned short*)(h + (size_t)kROWS * kDM);  // 8192*512
    unsigned short* xbuf  = ub    + (size_t)kROWS * kDM;        // 8192*1024 (x-half / y / ffn1 lo)
    unsigned short* tbuf  = xbuf  + (size_t)kROWS * kDI;        // 8192*1024 (dt / ffn1 hi / hb)
    unsigned short* xhb   = tbuf  + (size_t)kROWS * kDI;        // 8192*1024 (xh row-major)
    unsigned short* gateb = xhb   + (size_t)kROWS * kDI;        // 8192*1024 (gate row-major)
    unsigned short* dbl   = gateb + (size_t)kROWS * kDI;        // 8192*64 bf16
    float* dblF  = (float*)(dbl + (size_t)kROWS * 64);          // 8192*32 f32 (B/C)
    float* score = dblF + (size_t)kROWS * 32;                   // 8192
    float* smw   = score + kROWS;                               // 8192
    float* zcat  = smw   + kROWS;                               // 4096
    unsigned short* wts  = (unsigned short*)(zcat + kB * 2 * kDM);
    float* PL  = (float*)(wts + O_WTOT);                        // 8*32*16*1024 f32 = 16.8MB
    float* SDT = PL + (size_t)kB2 * kG * 16 * kDI;              // 8*32*1024 f32 = 1MB

    // ---- weight prep: fp32 [L][K][N] -> bf16 [L][N][K] (one launch) ----
    WJobs jobs;
    jobs.s[0] = fp[2];  jobs.s[1] = bp[2];
    jobs.s[2] = fp[5];  jobs.s[3] = bp[5];
    jobs.s[4] = fp[6];  jobs.s[5] = bp[6];
    jobs.s[6] = fp[10]; jobs.s[7] = bp[10];
    jobs.s[8] = fp[13]; jobs.s[9] = bp[13];
    jobs.s[10] = fp[15]; jobs.s[11] = bp[15];
    jobs.s[12] = aw1;
    int wblocks = 0;
    {
        const int wK[13] = {512,512,1024,1024,32,32,1024,1024,512,512,2048,2048,512};
        const int wN[13] = {2048,2048,64,64,1024,1024,512,512,2048,2048,512,512,256};
        const int wL[13] = {2,2,2,2,2,2,2,2,2,2,2,2,1};
        for (int j = 0; j < 13; j++) wblocks += wL[j] * (wK[j]/32) * (wN[j]/32);
    }
    wprep_k<<<wblocks, 256, 0, stream>>>(jobs, wts);

    init_h_k<<<kROWS * kDM / 256, 256, 0, stream>>>(x, h);

    for (int l = 0; l < kL; l++) {
        const float *f_n1w = fp[0]  + l * kDM,            *b_n1w = bp[0]  + l * kDM;
        const float *f_n1b = fp[1]  + l * kDM,            *b_n1b = bp[1]  + l * kDM;
        const float *f_cw  = fp[3]  + l * kDI * kDC,      *b_cw  = bp[3]  + l * kDI * kDC;
        const float *f_cb  = fp[4]  + l * kDI,            *b_cb  = bp[4]  + l * kDI;
        const float *f_dtb = fp[7]  + l * kDI,            *b_dtb = bp[7]  + l * kDI;
        const float *f_alog= fp[8]  + l * kDI * kDS,      *b_alog= bp[8]  + l * kDI * kDS;
        const float *f_dd  = fp[9]  + l * kDI,            *b_dd  = bp[9]  + l * kDI;
        const float *f_n2w = fp[11] + l * kDM,            *b_n2w = bp[11] + l * kDM;
        const float *f_n2b = fp[12] + l * kDM,            *b_n2b = bp[12] + l * kDM;
        const float *f_b1  = fp[14] + l * 4 * kDM,        *b_b1  = bp[14] + l * 4 * kDM;
        const float *f_b2  = fp[16] + l * kDM,            *b_b2  = bp[16] + l * kDM;

        const unsigned short *wInwF = wts + O_INW_F + (size_t)l * 2048 * 512;
        const unsigned short *wInwB = wts + O_INW_B + (size_t)l * 2048 * 512;
        const unsigned short *wXpwF = wts + O_XPW_F + (size_t)l * 64 * 1024;
        const unsigned short *wXpwB = wts + O_XPW_B + (size_t)l * 64 * 1024;
        const unsigned short *wDtwF = wts + O_DTW_F + (size_t)l * 1024 * 32;
        const unsigned short *wDtwB = wts + O_DTW_B + (size_t)l * 1024 * 32;
        const unsigned short *wOwF  = wts + O_OW_F  + (size_t)l * 512 * 1024;
        const unsigned short *wOwB  = wts + O_OW_B  + (size_t)l * 512 * 1024;
        const unsigned short *wW1F  = wts + O_W1_F  + (size_t)l * 2048 * 512;
        const unsigned short *wW1B  = wts + O_W1_B  + (size_t)l * 2048 * 512;
        const unsigned short *wW2F  = wts + O_W2_F  + (size_t)l * 512 * 2048;
        const unsigned short *wW2B  = wts + O_W2_B  + (size_t)l * 512 * 2048;

        // u = LN1(h) -> bf16
        ln_k<kDM,1><<<kROWS, 256, 0, stream>>>(h, f_n1w, b_n1w, f_n1b, b_n1b, ub);
        // x-half -> xbuf bf16 [row][kDI]; z-half -> gateb = silu(z) row-major
        gemm_mfma<128,128,EPI_NONE,0,MODE_GATE,1,64,512,4><<<dim3(16, 64), 512, 0, stream>>>(
            ub, kDM, kDM, wInwF, wInwB, nullptr, nullptr, xbuf, kDI, gateb);
        // xh[row][kDI] = silu(conv(xbuf) + cb)  (2-wide vectorized)
        conv_k<<<dim3(kN/64, kDI/64, kB2), 256, 0, stream>>>(
            xbuf, f_cw, b_cw, f_cb, b_cb, xhb);
        // dbl = xh @ xpw; cols>=32 also -> dblF f32 [row][32]
        // 32x32 tile -> 512 blocks (was 256 = 1 wave/SIMD, latency-starved)
        gemm_mfma<32,32,EPI_NONE,0,MODE_DBL,1,64><<<dim3(2, 256), 256, 0, stream>>>(
            xhb, kDI, kDI, wXpwF, wXpwB, nullptr, nullptr, dbl, 64, (unsigned short*)dblF);
        // dt[row][kDI] = softplus(dbl[:, :32] @ dtw + dtb)  (512 thr)
        gemm_mfma<128,128,EPI_SOFTPLUS,0,MODE_N,1,32,512><<<dim3(8, 64), 512, 0, stream>>>(
            dbl, 64, kDTR, wDtwF, wDtwB, f_dtb, b_dtb, tbuf, kDI, nullptr);
        // blocked scan: local pass -> boundary fix -> full pass (y into xbuf)
        bscan_k<0><<<dim3(kDI/256, kG, kB2), 256, 0, stream>>>(
            tbuf, xhb, gateb, dblF, xbuf, PL, SDT, f_alog, b_alog, f_dd, b_dd);
        bfix_k<<<kB2 * kDI * kDS / 256, 256, 0, stream>>>(PL, SDT, f_alog, b_alog);
        bscan_k<1><<<dim3(kDI/256, kG, kB2), 256, 0, stream>>>(
            tbuf, xhb, gateb, dblF, xbuf, PL, SDT, f_alog, b_alog, f_dd, b_dd);
        // h += y @ ow  (512-thread / 8-wave blocks, 4M x 2N)
        gemm_mfma<128,64,EPI_RESID,0,MODE_N,0,64,512,2><<<dim3(8, 64), 512, 0, stream>>>(
            xbuf, kDI, kDI, wOwF, wOwB, nullptr, nullptr, h, kDM, nullptr);
        // u = LN2(h) -> bf16
        ln_k<kDM,1><<<kROWS, 256, 0, stream>>>(h, f_n2w, b_n2w, f_n2b, b_n2b, ub);
        // ffn1: gelu(u @ w1 + b1) -> xbuf..tbuf slab bf16 (8192 x 2048)
        gemm_mfma<128,128,EPI_GELU,0,MODE_N,1,64,512,4><<<dim3(16, 64), 512, 0, stream>>>(
            ub, kDM, kDM, wW1F, wW1B, f_b1, b_b1, xbuf, 4*kDM, nullptr);
        // h += ffn1 @ w2 + b2; last layer also emits bf16 h into tbuf
        if (l == kL - 1) {
            gemm_mfma<128,64,EPI_RESID_BIAS,0,MODE_RESB16,0,64,512,2><<<dim3(8, 64), 512, 0, stream>>>(
                xbuf, 4*kDM, 4*kDM, wW2F, wW2B, f_b2, b_b2, h, kDM, tbuf);
        } else {
            gemm_mfma<128,64,EPI_RESID_BIAS,0,MODE_N,0,64,512,2><<<dim3(8, 64), 512, 0, stream>>>(
                xbuf, 4*kDM, 4*kDM, wW2F, wW2B, f_b2, b_b2, h, kDM, nullptr);
        }
    }

    // attention: u = tanh(hb @ aw1 + ab1) bf16 (hb = tbuf, emitted by w2)
    gemm_mfma<64,128,EPI_TANH,0,MODE_N,1,64,512,4><<<dim3(2, 128), 512, 0, stream>>>(
        tbuf, kDM, kDM, wts + O_AW1, wts + O_AW1, ab1, ab1, ub, 256, nullptr);
    att_score_k<<<kROWS / 4, 256, 0, stream>>>(ub, aw2, ab2, score);
    softmax_k<<<kB2, 256, 0, stream>>>(score, smw, zcat);   // also zeroes zcat
    pool_k<<<dim3(kB2, 32), 512, 0, stream>>>(smw, h, zcat);
    // out[0:4096] = LN(concat(zf, zb))
    ln_k<2*kDM,0><<<kB, 256, 0, stream>>>(zcat, nw, nw, nb, nb, out);
    // out[4096:8192] = 0.5*(af + flip(ab))
    att_out_k<<<kB * kN / 256, 256, 0, stream>>>(smw, out + kB * 2 * kDM);
}